// Round 12
// baseline (231.938 us; speedup 1.0000x reference)
//
#include <hip/hip_runtime.h>
#include <math.h>

#define B_  2
#define S_  2048
#define DM_ 2048
#define H_  16
#define DK_ 128
#define M_  (B_ * S_)

typedef __attribute__((ext_vector_type(8))) short bf16x8;
typedef __attribute__((ext_vector_type(4))) float f32x4;
typedef __attribute__((ext_vector_type(16))) float f32x16;
typedef unsigned short ushort_t;
typedef unsigned int uint_t;

__device__ inline ushort_t f2bf(float f) {
  union { float f; uint_t u; } v; v.f = f;
  uint_t u = v.u;
  uint_t r = (u + 0x7FFFu + ((u >> 16) & 1u)) >> 16;  // RNE
  return (ushort_t)r;
}

__device__ __forceinline__ uint_t cvt_pk_bf16(float a, float b) {
  uint_t r;
  asm("v_cvt_pk_bf16_f32 %0, %1, %2" : "=v"(r) : "v"(a), "v"(b));
  return r;  // lo16 = bf16(a), hi16 = bf16(b)
}

__device__ __forceinline__ float exp2_fast(float x) {
  float r;
  asm("v_exp_f32 %0, %1" : "=v"(r) : "v"(x));
  return r;  // 2^x
}

// ---------------------------------------------------------------------------
// RoPE table: tab[s*64 + i] = (cos, sin) of pos[s] * 10000^(-i/64)
// ---------------------------------------------------------------------------
__global__ void rope_tab_k(const int* __restrict__ pos,
                           float2* __restrict__ tab) {
  int idx = blockIdx.x * 256 + threadIdx.x;
  int s = idx >> 6, i = idx & 63;
  float ang = (float)pos[s] * exp2f((float)i * -0.2076205059304601f);
  float sn, cs;
  sincosf(ang, &sn, &cs);
  tab[idx] = make_float2(cs, sn);
}

// ---------------------------------------------------------------------------
// fp32 [K][N] -> bf16 [N][K] tiled transpose-convert (64x64 tiles)
// ---------------------------------------------------------------------------
__global__ __launch_bounds__(256) void tconv_k(const float* __restrict__ W,
                                               ushort_t* __restrict__ WT,
                                               int K, int N) {
  __shared__ ushort_t Ls[64][72];
  const int k0 = blockIdx.y * 64, n0 = blockIdx.x * 64;
  const int t = threadIdx.x;
  const int r = t >> 4, c4 = t & 15;
#pragma unroll
  for (int i = 0; i < 4; ++i) {
    int row = r + i * 16;
    float4 v = *(const float4*)(W + (size_t)(k0 + row) * N + n0 + c4 * 4);
    Ls[row][c4 * 4 + 0] = f2bf(v.x);
    Ls[row][c4 * 4 + 1] = f2bf(v.y);
    Ls[row][c4 * 4 + 2] = f2bf(v.z);
    Ls[row][c4 * 4 + 3] = f2bf(v.w);
  }
  __syncthreads();
#pragma unroll
  for (int i = 0; i < 4; ++i) {
    int chunk = t + i * 256;
    int nr = chunk >> 4, kc = chunk & 15;
    uint2 pk;
    pk.x = (uint_t)Ls[kc * 4 + 0][nr] | ((uint_t)Ls[kc * 4 + 1][nr] << 16);
    pk.y = (uint_t)Ls[kc * 4 + 2][nr] | ((uint_t)Ls[kc * 4 + 3][nr] << 16);
    *(uint2*)(WT + (size_t)(n0 + nr) * K + k0 + kc * 4) = pk;
  }
}

// ---------------------------------------------------------------------------
// bf16 [b*S+s][128] -> bf16 [b][128][S] transpose (per-batch V^T)
// ---------------------------------------------------------------------------
__global__ __launch_bounds__(256) void vtrans_k(const ushort_t* __restrict__ Vb,
                                                ushort_t* __restrict__ Vt) {
  __shared__ ushort_t Ls[64][72];
  const int s0 = blockIdx.x * 64, d0 = blockIdx.y * 64, b = blockIdx.z;
  const int t = threadIdx.x;
#pragma unroll
  for (int i = 0; i < 2; ++i) {
    int c = t + i * 256;
    int row = c >> 3, c8 = c & 7;
    *(bf16x8*)&Ls[row][c8 * 8] =
        *(const bf16x8*)(Vb + ((size_t)b * S_ + s0 + row) * DK_ + d0 + c8 * 8);
  }
  __syncthreads();
#pragma unroll
  for (int i = 0; i < 2; ++i) {
    int c = t + i * 256;
    int dr = c >> 3, s8 = c & 7;
    uint4 pk;
    pk.x = (uint_t)Ls[s8 * 8 + 0][dr] | ((uint_t)Ls[s8 * 8 + 1][dr] << 16);
    pk.y = (uint_t)Ls[s8 * 8 + 2][dr] | ((uint_t)Ls[s8 * 8 + 3][dr] << 16);
    pk.z = (uint_t)Ls[s8 * 8 + 4][dr] | ((uint_t)Ls[s8 * 8 + 5][dr] << 16);
    pk.w = (uint_t)Ls[s8 * 8 + 6][dr] | ((uint_t)Ls[s8 * 8 + 7][dr] << 16);
    *(uint4*)(Vt + ((size_t)b * DK_ + d0 + dr) * S_ + s0 + s8 * 8) = pk;
  }
}

// ---------------------------------------------------------------------------
// bf16 MFMA GEMM: C = A[M x K] @ Bt[N x K]^T + bias, LDS-staged epilogue.
// 128x64 tile (BM=128, BN=64), BK=32, 4 waves (2x2 over 64x32 sub-tiles),
// 16x16x32 MFMA. Grid 4-4.5 blocks/CU for latency hiding (vs 2.25 at 128^2).
// CONVA: 0 = A is bf16, staged via global_load_lds(16B)
//        1 = A is fp32, reg-staged (T14 prefetch) + cvt_pk -> ds_write_b128
// EPI:   0 = fp32 out to C1 (stride N), bias b1
//        1 = fused QKV: gcol<2048 -> RoPE+bf16 Q (C1); 2048..2175 ->
//            RoPE+bf16 K (C2); 2176..2303 -> bf16 V (C3)
// ---------------------------------------------------------------------------
template <int EPI, int CONVA>
__global__ __launch_bounds__(256) void gemm_mfma_k(
    const void* __restrict__ Av, const ushort_t* __restrict__ Bt,
    const float* __restrict__ b1, const float* __restrict__ b2,
    const float* __restrict__ b3, const float2* __restrict__ tab,
    void* __restrict__ C1, void* __restrict__ C2, void* __restrict__ C3,
    int N, int K) {
  __shared__ ushort_t Abuf[128 * 32];
  __shared__ ushort_t Bbuf[64 * 32];
  __shared__ float Ep[32][68];

  const ushort_t* A = (const ushort_t*)Av;
  const float* Af = (const float*)Av;

  const int nwg = gridDim.x * gridDim.y;
  const int orig = blockIdx.y * gridDim.x + blockIdx.x;
  const int qq = nwg >> 3;
  const int swz = (orig & 7) * qq + (orig >> 3);
  const int bx = swz % gridDim.x, by = swz / gridDim.x;

  const int tid = threadIdx.x;
  const int lane = tid & 63;
  const int lr = lane & 15, lg = lane >> 4;
  const int w = tid >> 6, wm = w >> 1, wn = w & 1;
  const int row0 = by * 128, col0 = bx * 64;

  f32x4 acc[4][2];
#pragma unroll
  for (int i = 0; i < 4; ++i)
#pragma unroll
    for (int j = 0; j < 2; ++j) acc[i][j] = (f32x4){0.f, 0.f, 0.f, 0.f};

  // CONVA=1: A prefetch registers (2 units x 8 floats); unit u = tid + i*256,
  // row = u>>2 (0..127), kc = u&3 (8-col group within BK=32)
  float4 ar0[2], ar1[2];
#define ALOAD(K0)                                                         \
  {                                                                       \
    _Pragma("unroll") for (int i = 0; i < 2; ++i) {                       \
      int u = tid + i * 256;                                              \
      const float* ap = Af + (size_t)(row0 + (u >> 2)) * K + (K0) + (u & 3) * 8; \
      ar0[i] = *(const float4*)ap;                                        \
      ar1[i] = *(const float4*)(ap + 4);                                  \
    }                                                                     \
  }

  if (CONVA) ALOAD(0);

  for (int k0 = 0; k0 < K; k0 += 32) {
    __syncthreads();
    if (CONVA) {
#pragma unroll
      for (int i = 0; i < 2; ++i) {
        int u = tid + i * 256;
        uint4 pk;
        pk.x = cvt_pk_bf16(ar0[i].x, ar0[i].y);
        pk.y = cvt_pk_bf16(ar0[i].z, ar0[i].w);
        pk.z = cvt_pk_bf16(ar1[i].x, ar1[i].y);
        pk.w = cvt_pk_bf16(ar1[i].z, ar1[i].w);
        *(uint4*)&Abuf[(u >> 2) * 32 + (u & 3) * 8] = pk;
      }
      if (tid < 256) {  // B: 256 chunks of 16B
        int c = tid;
        __builtin_amdgcn_global_load_lds(
            (const __attribute__((address_space(1))) void*)(
                Bt + (size_t)(col0 + (c >> 2)) * K + k0 + (c & 3) * 8),
            (__attribute__((address_space(3))) void*)(Bbuf + c * 8), 16, 0, 0);
      }
      if (k0 + 32 < K) ALOAD(k0 + 32);
    } else {
#pragma unroll
      for (int i = 0; i < 2; ++i) {
        int c = tid + i * 256;
        __builtin_amdgcn_global_load_lds(
            (const __attribute__((address_space(1))) void*)(
                A + (size_t)(row0 + (c >> 2)) * K + k0 + (c & 3) * 8),
            (__attribute__((address_space(3))) void*)(Abuf + c * 8), 16, 0, 0);
      }
      {
        int c = tid;
        __builtin_amdgcn_global_load_lds(
            (const __attribute__((address_space(1))) void*)(
                Bt + (size_t)(col0 + (c >> 2)) * K + k0 + (c & 3) * 8),
            (__attribute__((address_space(3))) void*)(Bbuf + c * 8), 16, 0, 0);
      }
    }
    __syncthreads();

    bf16x8 af[4], bfr[2];
#pragma unroll
    for (int i = 0; i < 4; ++i)
      af[i] = *(const bf16x8*)&Abuf[(wm * 64 + i * 16 + lr) * 32 + lg * 8];
#pragma unroll
    for (int j = 0; j < 2; ++j)
      bfr[j] = *(const bf16x8*)&Bbuf[(wn * 32 + j * 16 + lr) * 32 + lg * 8];
#pragma unroll
    for (int mi = 0; mi < 4; ++mi)
#pragma unroll
      for (int ni = 0; ni < 2; ++ni)
        acc[mi][ni] = __builtin_amdgcn_mfma_f32_16x16x32_bf16(
            af[mi], bfr[ni], acc[mi][ni], 0, 0, 0);
  }
#undef ALOAD

  // ---- LDS-staged epilogue: 4 rounds of [32 rows x 64 cols] fp32
  const int r5 = tid >> 3;            // 0..31 staged row
  const int c0 = (tid & 7) * 8;       // 0..56 col base (8 cols/thread)
  const int lrow = (r5 >> 4) * 64 + (r5 & 15);
  const int gcol = col0 + c0;

#pragma unroll
  for (int mi = 0; mi < 4; ++mi) {
    __syncthreads();
#pragma unroll
    for (int ni = 0; ni < 2; ++ni)
#pragma unroll
      for (int j = 0; j < 4; ++j)
        Ep[wm * 16 + lg * 4 + j][wn * 32 + ni * 16 + lr] = acc[mi][ni][j];
    __syncthreads();

    const int grow = row0 + lrow + mi * 16;
    float v[8];
#pragma unroll
    for (int q4 = 0; q4 < 2; ++q4) {
      float4 f = *(const float4*)&Ep[r5][c0 + q4 * 4];
      v[q4 * 4 + 0] = f.x; v[q4 * 4 + 1] = f.y;
      v[q4 * 4 + 2] = f.z; v[q4 * 4 + 3] = f.w;
    }

    if (EPI == 0) {
      float* Cp = (float*)C1 + (size_t)grow * N + gcol;
#pragma unroll
      for (int q4 = 0; q4 < 2; ++q4) {
        float4 bb = *(const float4*)&b1[gcol + q4 * 4];
        float4 o;
        o.x = v[q4 * 4 + 0] + bb.x; o.y = v[q4 * 4 + 1] + bb.y;
        o.z = v[q4 * 4 + 2] + bb.z; o.w = v[q4 * 4 + 3] + bb.w;
        *(float4*)(Cp + q4 * 4) = o;
      }
    } else {
      const int s = grow & (S_ - 1);
      ushort_t hs[8];
      ushort_t* Cp;
      if (gcol < DM_) {               // Q: RoPE
        const float2* tp = tab + (size_t)s * 64 + ((gcol & 127) >> 1);
        const float* bb = b1 + gcol;
#pragma unroll
        for (int p = 0; p < 4; ++p) {
          float2 cs = tp[p];
          float v0 = v[2 * p] + bb[2 * p], v1 = v[2 * p + 1] + bb[2 * p + 1];
          hs[2 * p]     = f2bf(v0 * cs.x - v1 * cs.y);
          hs[2 * p + 1] = f2bf(v0 * cs.y + v1 * cs.x);
        }
        Cp = (ushort_t*)C1 + (size_t)grow * DM_ + gcol;
      } else if (gcol < DM_ + DK_) {  // K: RoPE
        const int c = gcol - DM_;
        const float2* tp = tab + (size_t)s * 64 + (c >> 1);
        const float* bb = b2 + c;
#pragma unroll
        for (int p = 0; p < 4; ++p) {
          float2 cs = tp[p];
          float v0 = v[2 * p] + bb[2 * p], v1 = v[2 * p + 1] + bb[2 * p + 1];
          hs[2 * p]     = f2bf(v0 * cs.x - v1 * cs.y);
          hs[2 * p + 1] = f2bf(v0 * cs.y + v1 * cs.x);
        }
        Cp = (ushort_t*)C2 + (size_t)grow * DK_ + c;
      } else {                        // V: plain bias
        const int c = gcol - DM_ - DK_;
#pragma unroll
        for (int kk = 0; kk < 8; ++kk) hs[kk] = f2bf(v[kk] + b3[c + kk]);
        Cp = (ushort_t*)C3 + (size_t)grow * DK_ + c;
      }
      uint4 u0;
      u0.x = (uint_t)hs[0] | ((uint_t)hs[1] << 16);
      u0.y = (uint_t)hs[2] | ((uint_t)hs[3] << 16);
      u0.z = (uint_t)hs[4] | ((uint_t)hs[5] << 16);
      u0.w = (uint_t)hs[6] | ((uint_t)hs[7] << 16);
      *(uint4*)Cp = u0;
    }
  }
}

// ---------------------------------------------------------------------------
// Causal MQA flash attention v7: 32x32x16 MFMA, in-register P, balanced
// A/B waves, 128-kv macro-staging, exp2-domain softmax + T13 defer-max.
// ---------------------------------------------------------------------------
__global__ __launch_bounds__(512) void attn_mfma7_k(
    const ushort_t* __restrict__ Q, const ushort_t* __restrict__ K,
    const ushort_t* __restrict__ Vt, ushort_t* __restrict__ O) {
  __shared__ ushort_t Ksh[128][136];   // [kv][d]
  __shared__ ushort_t Vsh[128][136];   // [d][kv] (V^T), kv = 128 per macro

  const int bx = blockIdx.x;          // 0..31
  const int hg = blockIdx.y, b = blockIdx.z;
  const int tid = threadIdx.x;
  const int w = tid >> 6, lane = tid & 63;
  const int lq = lane & 31, hi = lane >> 5;
  const int h = hg * 4 + (w & 3);
  const int qt = (w < 4) ? bx : (63 - bx);
  const int q0 = qt * 32;
  const int qg = q0 + lq;
  const int nt = (qt >> 1) + 1;                 // 64-kv steps this wave
  const int ntB = ((63 - bx) >> 1) + 1;         // max 64-kv steps in block
  const int nT = (ntB + 1) >> 1;                // 128-kv macro steps
  const size_t bS = (size_t)b * S_;

  bf16x8 qf[8];
  {
    const ushort_t* qp = Q + (bS + qg) * DM_ + h * DK_ + hi * 8;
#pragma unroll
    for (int kg = 0; kg < 8; ++kg) qf[kg] = *(const bf16x8*)(qp + kg * 16);
  }

  f32x16 oacc[4];
#pragma unroll
  for (int dt = 0; dt < 4; ++dt)
#pragma unroll
    for (int i = 0; i < 16; ++i) oacc[dt][i] = 0.f;
  float m = -INFINITY, l = 0.f;

  bf16x8 kreg[4], vreg[4];
#define ISSUE_LOADS(T0)                                                      \
  {                                                                          \
    const int kv_ = (T0) * 128;                                              \
    _Pragma("unroll") for (int i = 0; i < 4; ++i) {                          \
      int u = tid + i * 512;                                                 \
      kreg[i] = *(const bf16x8*)(K + (bS + kv_ + (u >> 4)) * DK_ + (u & 15) * 8); \
      vreg[i] = *(const bf16x8*)(Vt + ((size_t)b * DK_ + (u >> 4)) * S_ + kv_ + (u & 15) * 8); \
    }                                                                        \
  }

  ISSUE_LOADS(0);

  for (int T = 0; T < nT; ++T) {
    __syncthreads();  // previous macro-tile's LDS reads done
#pragma unroll
    for (int i = 0; i < 4; ++i) {
      int u = tid + i * 512;
      *(bf16x8*)&Ksh[u >> 4][(u & 15) * 8] = kreg[i];
      *(bf16x8*)&Vsh[u >> 4][(u & 15) * 8] = vreg[i];
    }
    if (T + 1 < nT) ISSUE_LOADS(T + 1);
    __syncthreads();  // macro-tile staged

#pragma unroll
    for (int hf = 0; hf < 2; ++hf) {
      const int s64 = 2 * T + hf;
      if (s64 < nt) {
        const int kv0 = s64 * 64;
        const int ko = hf * 64;

        // ---- QK^T: st[kt] = S^T 32x32 tile
        f32x16 st[2];
#pragma unroll
        for (int kt = 0; kt < 2; ++kt)
#pragma unroll
          for (int i = 0; i < 16; ++i) st[kt][i] = 0.f;
        __builtin_amdgcn_s_setprio(1);
#pragma unroll
        for (int kg = 0; kg < 8; ++kg) {
          bf16x8 kf0 = *(const bf16x8*)&Ksh[ko + lq][kg * 16 + hi * 8];
          bf16x8 kf1 = *(const bf16x8*)&Ksh[ko + 32 + lq][kg * 16 + hi * 8];
          st[0] = __builtin_amdgcn_mfma_f32_32x32x16_bf16(kf0, qf[kg], st[0], 0, 0, 0);
          st[1] = __builtin_amdgcn_mfma_f32_32x32x16_bf16(kf1, qf[kg], st[1], 0, 0, 0);
        }
        __builtin_amdgcn_s_setprio(0);

        // ---- online softmax (base-2 domain)
        const float SCL2 = 0.1275174348767325f;  // (1/sqrt(128)) * log2(e)
        const bool need_mask = (kv0 + 63) > q0;
        float tmax = -INFINITY;
#pragma unroll
        for (int kt = 0; kt < 2; ++kt)
#pragma unroll
          for (int r = 0; r < 16; ++r) {
            float s = st[kt][r] * SCL2;
            if (need_mask) {
              int kvi = kv0 + kt * 32 + (r & 3) + 8 * (r >> 2) + 4 * hi;
              if (kvi > qg) s = -INFINITY;
            }
            st[kt][r] = s;
            tmax = fmaxf(tmax, s);
          }
        tmax = fmaxf(tmax, __shfl_xor(tmax, 32));
        if (__any(tmax > m + 8.f)) {  // T13 defer-max
          float mnew = fmaxf(m, tmax);
          float corr = exp2_fast(m - mnew);  // first tile: 2^-inf = 0
          l *= corr;
#pragma unroll
          for (int dt = 0; dt < 4; ++dt)
#pragma unroll
            for (int i = 0; i < 16; ++i) oacc[dt][i] *= corr;
          m = mnew;
        }
        float psum = 0.f;
#pragma unroll
        for (int kt = 0; kt < 2; ++kt)
#pragma unroll
          for (int r = 0; r < 16; ++r) {
            float p = exp2_fast(st[kt][r] - m);  // bounded by 2^8
            st[kt][r] = p;
            psum += p;
          }
        psum += __shfl_xor(psum, 32);
        l += psum;

        // ---- P -> PV B-frags in-register
        uint_t wn[2][4][2], wp[2][4][2];
#pragma unroll
        for (int kt = 0; kt < 2; ++kt)
#pragma unroll
          for (int rb = 0; rb < 4; ++rb)
#pragma unroll
            for (int p = 0; p < 2; ++p) {
              wn[kt][rb][p] = cvt_pk_bf16(st[kt][4 * rb + 2 * p],
                                          st[kt][4 * rb + 2 * p + 1]);
              wp[kt][rb][p] = (uint_t)__shfl_xor((int)wn[kt][rb][p], 32);
            }
        bf16x8 pf[4];
#pragma unroll
        for (int ks = 0; ks < 4; ++ks) {
          const int kt = ks >> 1, rb = 2 * (ks & 1);
          uint4 u;
          u.x = hi ? wp[kt][rb + 1][0] : wn[kt][rb][0];
          u.y = hi ? wp[kt][rb + 1][1] : wn[kt][rb][1];
          u.z = hi ? wn[kt][rb + 1][0] : wp[kt][rb][0];
          u.w = hi ? wn[kt][rb + 1][1] : wp[kt][rb][1];
          pf[ks] = *(bf16x8*)&u;
        }

        // ---- PV: O^T += V^T · P^T
        __builtin_amdgcn_s_setprio(1);
#pragma unroll
        for (int dt = 0; dt < 4; ++dt)
#pragma unroll
          for (int ks = 0; ks < 4; ++ks) {
            bf16x8 vf = *(const bf16x8*)&Vsh[dt * 32 + lq][ko + ks * 16 + hi * 8];
            oacc[dt] = __builtin_amdgcn_mfma_f32_32x32x16_bf16(vf, pf[ks], oacc[dt], 0, 0, 0);
          }
        __builtin_amdgcn_s_setprio(0);
      }
    }
  }
#undef ISSUE_LOADS

  // ---- epilogue: lane q = qg; d = dt*32 + 8*rb + 4*hi + (0..3)
  const float invl = 1.0f / l;
  ushort_t* op = O + (bS + qg) * DM_ + h * DK_;
#pragma unroll
  for (int dt = 0; dt < 4; ++dt)
#pragma unroll
    for (int rb = 0; rb < 4; ++rb) {
      uint2 pk;
      pk.x = cvt_pk_bf16(oacc[dt][4 * rb + 0] * invl,
                         oacc[dt][4 * rb + 1] * invl);
      pk.y = cvt_pk_bf16(oacc[dt][4 * rb + 2] * invl,
                         oacc[dt][4 * rb + 3] * invl);
      *(uint2*)(op + dt * 32 + 8 * rb + 4 * hi) = pk;
    }
}

// ---------------------------------------------------------------------------
extern "C" void kernel_launch(void* const* d_in, const int* in_sizes, int n_in,
                              void* d_out, int out_size, void* d_ws,
                              size_t ws_size, hipStream_t stream) {
  const float* x  = (const float*)d_in[0];
  const int*   tp = (const int*)d_in[1];
  const float* Wq = (const float*)d_in[2];
  const float* bq = (const float*)d_in[3];
  const float* Wk = (const float*)d_in[4];
  const float* bk = (const float*)d_in[5];
  const float* Wv = (const float*)d_in[6];
  const float* bv = (const float*)d_in[7];
  const float* Wo = (const float*)d_in[8];
  const float* bo = (const float*)d_in[9];
  float* out = (float*)d_out;

  const int NQKV = DM_ + 2 * DK_;  // 2304
  ushort_t* WqkvT = (ushort_t*)d_ws;                    // 2304*DM  9.5 MB
  ushort_t* WoT   = WqkvT + (size_t)NQKV * DM_;         // DM*DM    8 MB
  ushort_t* Qbf   = WoT + (size_t)DM_ * DM_;            // M*DM     16 MB
  ushort_t* Kbf   = Qbf + (size_t)M_ * DM_;             // M*DK     1 MB
  ushort_t* Vbf   = Kbf + (size_t)M_ * DK_;             // M*DK     1 MB
  ushort_t* Vtb   = Vbf + (size_t)M_ * DK_;             // B*DK*S   1 MB
  float2*   tab   = (float2*)(Vtb + (size_t)M_ * DK_);  // S*64     1 MB
  ushort_t* ATb   = (ushort_t*)(tab + (size_t)S_ * 64); // M*DM     16 MB

  tconv_k<<<dim3(DM_ / 64, DM_ / 64), 256, 0, stream>>>(Wq, WqkvT, DM_, DM_);
  tconv_k<<<dim3(DK_ / 64, DM_ / 64), 256, 0, stream>>>(
      Wk, WqkvT + (size_t)DM_ * DM_, DM_, DK_);
  tconv_k<<<dim3(DK_ / 64, DM_ / 64), 256, 0, stream>>>(
      Wv, WqkvT + (size_t)(DM_ + DK_) * DM_, DM_, DK_);
  tconv_k<<<dim3(DM_ / 64, DM_ / 64), 256, 0, stream>>>(Wo, WoT, DM_, DM_);
  rope_tab_k<<<S_ * 64 / 256, 256, 0, stream>>>(tp, tab);

  // Fused QKV projection (MFMA; fp32 A converted in-staging; Q,K get RoPE)
  gemm_mfma_k<1, 1><<<dim3(NQKV / 64, M_ / 128), 256, 0, stream>>>(
      (const void*)x, WqkvT, bq, bk, bv, tab, (void*)Qbf, (void*)Kbf,
      (void*)Vbf, NQKV, DM_);

  // V -> V^T per batch
  vtrans_k<<<dim3(S_ / 64, DK_ / 64, B_), 256, 0, stream>>>(Vbf, Vtb);

  // Causal MQA attention v7 (exp2 softmax, defer-max, 128-kv macro-stage)
  attn_mfma7_k<<<dim3(S_ / 64, H_ / 4, B_), 512, 0, stream>>>(
      Qbf, Kbf, Vtb, ATb);

  // Output projection (MFMA, fp32 out)
  gemm_mfma_k<0, 0><<<dim3(DM_ / 64, M_ / 128), 256, 0, stream>>>(
      (const void*)ATb, WoT, bo, nullptr, nullptr, nullptr, (void*)out,
      nullptr, nullptr, DM_, DM_);
}

// Round 13
// 221.646 us; speedup vs baseline: 1.0464x; 1.0464x over previous
//
#include <hip/hip_runtime.h>
#include <math.h>

#define B_  2
#define S_  2048
#define DM_ 2048
#define H_  16
#define DK_ 128
#define M_  (B_ * S_)

typedef __attribute__((ext_vector_type(8))) short bf16x8;
typedef __attribute__((ext_vector_type(4))) float f32x4;
typedef __attribute__((ext_vector_type(16))) float f32x16;
typedef unsigned short ushort_t;
typedef unsigned int uint_t;

__device__ inline ushort_t f2bf(float f) {
  union { float f; uint_t u; } v; v.f = f;
  uint_t u = v.u;
  uint_t r = (u + 0x7FFFu + ((u >> 16) & 1u)) >> 16;  // RNE
  return (ushort_t)r;
}

__device__ __forceinline__ uint_t cvt_pk_bf16(float a, float b) {
  uint_t r;
  asm("v_cvt_pk_bf16_f32 %0, %1, %2" : "=v"(r) : "v"(a), "v"(b));
  return r;  // lo16 = bf16(a), hi16 = bf16(b)
}

__device__ __forceinline__ float exp2_fast(float x) {
  float r;
  asm("v_exp_f32 %0, %1" : "=v"(r) : "v"(x));
  return r;  // 2^x
}

// ---------------------------------------------------------------------------
// RoPE table: tab[s*64 + i] = (cos, sin) of pos[s] * 10000^(-i/64)
// ---------------------------------------------------------------------------
__global__ void rope_tab_k(const int* __restrict__ pos,
                           float2* __restrict__ tab) {
  int idx = blockIdx.x * 256 + threadIdx.x;
  int s = idx >> 6, i = idx & 63;
  float ang = (float)pos[s] * exp2f((float)i * -0.2076205059304601f);
  float sn, cs;
  sincosf(ang, &sn, &cs);
  tab[idx] = make_float2(cs, sn);
}

// ---------------------------------------------------------------------------
// fp32 [K][N] -> bf16 [N][K] tiled transpose-convert (64x64 tiles)
// ---------------------------------------------------------------------------
__global__ __launch_bounds__(256) void tconv_k(const float* __restrict__ W,
                                               ushort_t* __restrict__ WT,
                                               int K, int N) {
  __shared__ ushort_t Ls[64][72];
  const int k0 = blockIdx.y * 64, n0 = blockIdx.x * 64;
  const int t = threadIdx.x;
  const int r = t >> 4, c4 = t & 15;
#pragma unroll
  for (int i = 0; i < 4; ++i) {
    int row = r + i * 16;
    float4 v = *(const float4*)(W + (size_t)(k0 + row) * N + n0 + c4 * 4);
    Ls[row][c4 * 4 + 0] = f2bf(v.x);
    Ls[row][c4 * 4 + 1] = f2bf(v.y);
    Ls[row][c4 * 4 + 2] = f2bf(v.z);
    Ls[row][c4 * 4 + 3] = f2bf(v.w);
  }
  __syncthreads();
#pragma unroll
  for (int i = 0; i < 4; ++i) {
    int chunk = t + i * 256;
    int nr = chunk >> 4, kc = chunk & 15;
    uint2 pk;
    pk.x = (uint_t)Ls[kc * 4 + 0][nr] | ((uint_t)Ls[kc * 4 + 1][nr] << 16);
    pk.y = (uint_t)Ls[kc * 4 + 2][nr] | ((uint_t)Ls[kc * 4 + 3][nr] << 16);
    *(uint2*)(WT + (size_t)(n0 + nr) * K + k0 + kc * 4) = pk;
  }
}

// ---------------------------------------------------------------------------
// bf16 [b*S+s][128] -> bf16 [b][128][S] transpose (per-batch V^T)
// ---------------------------------------------------------------------------
__global__ __launch_bounds__(256) void vtrans_k(const ushort_t* __restrict__ Vb,
                                                ushort_t* __restrict__ Vt) {
  __shared__ ushort_t Ls[64][72];
  const int s0 = blockIdx.x * 64, d0 = blockIdx.y * 64, b = blockIdx.z;
  const int t = threadIdx.x;
#pragma unroll
  for (int i = 0; i < 2; ++i) {
    int c = t + i * 256;
    int row = c >> 3, c8 = c & 7;
    *(bf16x8*)&Ls[row][c8 * 8] =
        *(const bf16x8*)(Vb + ((size_t)b * S_ + s0 + row) * DK_ + d0 + c8 * 8);
  }
  __syncthreads();
#pragma unroll
  for (int i = 0; i < 2; ++i) {
    int c = t + i * 256;
    int dr = c >> 3, s8 = c & 7;
    uint4 pk;
    pk.x = (uint_t)Ls[s8 * 8 + 0][dr] | ((uint_t)Ls[s8 * 8 + 1][dr] << 16);
    pk.y = (uint_t)Ls[s8 * 8 + 2][dr] | ((uint_t)Ls[s8 * 8 + 3][dr] << 16);
    pk.z = (uint_t)Ls[s8 * 8 + 4][dr] | ((uint_t)Ls[s8 * 8 + 5][dr] << 16);
    pk.w = (uint_t)Ls[s8 * 8 + 6][dr] | ((uint_t)Ls[s8 * 8 + 7][dr] << 16);
    *(uint4*)(Vt + ((size_t)b * DK_ + d0 + dr) * S_ + s0 + s8 * 8) = pk;
  }
}

// ---------------------------------------------------------------------------
// bf16 MFMA GEMM: C = A[M x K] @ Bt[N x K]^T + bias, LDS-staged epilogue.
// 128x128 tile, BK=32, 4 waves (2x2), 16x16x32 MFMA.
// T3-minimum double-buffer: next K-tile's loads are ISSUED before computing
// the current tile; the __syncthreads at step end drains them -> HBM/L2
// latency overlaps the MFMA+ds_read window (matters at 2.25 blocks/CU).
// CONVA: 0 = A is bf16, staged via global_load_lds(16B)
//        1 = A is fp32: regs hold tile t+1 (cvt_pk -> ds_write), ALOAD t+2
// EPI:   0 = fp32 out to C1 (stride N), bias b1
//        1 = fused QKV: gcol<2048 -> RoPE+bf16 Q (C1); 2048..2175 ->
//            RoPE+bf16 K (C2); 2176..2303 -> bf16 V (C3)
// ---------------------------------------------------------------------------
template <int EPI, int CONVA>
__global__ __launch_bounds__(256) void gemm_mfma_k(
    const void* __restrict__ Av, const ushort_t* __restrict__ Bt,
    const float* __restrict__ b1, const float* __restrict__ b2,
    const float* __restrict__ b3, const float2* __restrict__ tab,
    void* __restrict__ C1, void* __restrict__ C2, void* __restrict__ C3,
    int N, int K) {
  __shared__ ushort_t Abuf[2][128 * 32];
  __shared__ ushort_t Bbuf[2][128 * 32];
  __shared__ float Ep[32][132];

  const ushort_t* A = (const ushort_t*)Av;
  const float* Af = (const float*)Av;

  const int nwg = gridDim.x * gridDim.y;
  const int orig = blockIdx.y * gridDim.x + blockIdx.x;
  const int qq = nwg >> 3;
  const int swz = (orig & 7) * qq + (orig >> 3);
  const int bx = swz % gridDim.x, by = swz / gridDim.x;

  const int tid = threadIdx.x;
  const int lane = tid & 63;
  const int lr = lane & 15, lg = lane >> 4;
  const int w = tid >> 6, wm = w >> 1, wn = w & 1;
  const int row0 = by * 128, col0 = bx * 128;

  f32x4 acc[4][4];
#pragma unroll
  for (int i = 0; i < 4; ++i)
#pragma unroll
    for (int j = 0; j < 4; ++j) acc[i][j] = (f32x4){0.f, 0.f, 0.f, 0.f};

  float4 ar0[2], ar1[2];
#define ALOAD(K0)                                                         \
  {                                                                       \
    _Pragma("unroll") for (int i = 0; i < 2; ++i) {                       \
      int u = tid + i * 256;                                              \
      const float* ap = Af + (size_t)(row0 + (u >> 2)) * K + (K0) + (u & 3) * 8; \
      ar0[i] = *(const float4*)ap;                                        \
      ar1[i] = *(const float4*)(ap + 4);                                  \
    }                                                                     \
  }
#define CVT_WRITE(BUF)                                                    \
  {                                                                       \
    _Pragma("unroll") for (int i = 0; i < 2; ++i) {                       \
      int u = tid + i * 256;                                              \
      uint4 pk;                                                           \
      pk.x = cvt_pk_bf16(ar0[i].x, ar0[i].y);                             \
      pk.y = cvt_pk_bf16(ar0[i].z, ar0[i].w);                             \
      pk.z = cvt_pk_bf16(ar1[i].x, ar1[i].y);                             \
      pk.w = cvt_pk_bf16(ar1[i].z, ar1[i].w);                             \
      *(uint4*)&Abuf[BUF][(u >> 2) * 32 + (u & 3) * 8] = pk;              \
    }                                                                     \
  }
#define STAGE_A(BUF, K0)                                                  \
  {                                                                       \
    _Pragma("unroll") for (int i = 0; i < 2; ++i) {                       \
      int c = tid + i * 256;                                              \
      __builtin_amdgcn_global_load_lds(                                   \
          (const __attribute__((address_space(1))) void*)(                \
              A + (size_t)(row0 + (c >> 2)) * K + (K0) + (c & 3) * 8),    \
          (__attribute__((address_space(3))) void*)(&Abuf[BUF][c * 8]),   \
          16, 0, 0);                                                      \
    }                                                                     \
  }
#define STAGE_B(BUF, K0)                                                  \
  {                                                                       \
    _Pragma("unroll") for (int i = 0; i < 2; ++i) {                       \
      int c = tid + i * 256;                                              \
      __builtin_amdgcn_global_load_lds(                                   \
          (const __attribute__((address_space(1))) void*)(                \
              Bt + (size_t)(col0 + (c >> 2)) * K + (K0) + (c & 3) * 8),   \
          (__attribute__((address_space(3))) void*)(&Bbuf[BUF][c * 8]),   \
          16, 0, 0);                                                      \
    }                                                                     \
  }

  // ---- prologue: stage tile 0 into buffer 0
  if (CONVA) {
    ALOAD(0);
    CVT_WRITE(0);        // compiler waits on ar* regs
    STAGE_B(0, 0);
    if (K > 32) ALOAD(32);
  } else {
    STAGE_A(0, 0);
    STAGE_B(0, 0);
  }
  __syncthreads();       // drains vmcnt + lgkm; tile 0 ready

  int cur = 0;
  for (int k0 = 0; k0 < K; k0 += 32) {
    const int nxt = cur ^ 1;
    // ---- issue next tile's staging BEFORE computing current
    if (k0 + 32 < K) {
      if (CONVA) {
        CVT_WRITE(nxt);              // regs hold tile k0+32
        STAGE_B(nxt, k0 + 32);
        if (k0 + 64 < K) ALOAD(k0 + 64);
      } else {
        STAGE_A(nxt, k0 + 32);
        STAGE_B(nxt, k0 + 32);
      }
    }
    // ---- compute current tile
    bf16x8 af[4], bfr[4];
#pragma unroll
    for (int i = 0; i < 4; ++i) {
      af[i]  = *(const bf16x8*)&Abuf[cur][(wm * 64 + i * 16 + lr) * 32 + lg * 8];
      bfr[i] = *(const bf16x8*)&Bbuf[cur][(wn * 64 + i * 16 + lr) * 32 + lg * 8];
    }
#pragma unroll
    for (int mi = 0; mi < 4; ++mi)
#pragma unroll
      for (int ni = 0; ni < 4; ++ni)
        acc[mi][ni] = __builtin_amdgcn_mfma_f32_16x16x32_bf16(
            af[mi], bfr[ni], acc[mi][ni], 0, 0, 0);
    __syncthreads();     // drains next-tile loads (overlapped with compute)
    cur = nxt;
  }
#undef ALOAD
#undef CVT_WRITE
#undef STAGE_A
#undef STAGE_B

  const int r5 = tid >> 3;
  const int c0 = (tid & 7) * 16;
  const int lrow = (r5 >> 4) * 64 + (r5 & 15);
  const int gcol = col0 + c0;

#pragma unroll
  for (int mi = 0; mi < 4; ++mi) {
    __syncthreads();
#pragma unroll
    for (int ni = 0; ni < 4; ++ni)
#pragma unroll
      for (int j = 0; j < 4; ++j)
        Ep[wm * 16 + lg * 4 + j][wn * 64 + ni * 16 + lr] = acc[mi][ni][j];
    __syncthreads();

    const int grow = row0 + lrow + mi * 16;
    float v[16];
#pragma unroll
    for (int q4 = 0; q4 < 4; ++q4) {
      float4 f = *(const float4*)&Ep[r5][c0 + q4 * 4];
      v[q4 * 4 + 0] = f.x; v[q4 * 4 + 1] = f.y;
      v[q4 * 4 + 2] = f.z; v[q4 * 4 + 3] = f.w;
    }

    if (EPI == 0) {
      float* Cp = (float*)C1 + (size_t)grow * N + gcol;
#pragma unroll
      for (int q4 = 0; q4 < 4; ++q4) {
        float4 bb = *(const float4*)&b1[gcol + q4 * 4];
        float4 o;
        o.x = v[q4 * 4 + 0] + bb.x; o.y = v[q4 * 4 + 1] + bb.y;
        o.z = v[q4 * 4 + 2] + bb.z; o.w = v[q4 * 4 + 3] + bb.w;
        *(float4*)(Cp + q4 * 4) = o;
      }
    } else {
      const int s = grow & (S_ - 1);
      ushort_t hs[16];
      ushort_t* Cp;
      if (gcol < DM_) {               // Q: RoPE
        const float2* tp = tab + (size_t)s * 64 + ((gcol & 127) >> 1);
        const float* bb = b1 + gcol;
#pragma unroll
        for (int p = 0; p < 8; ++p) {
          float2 cs = tp[p];
          float v0 = v[2 * p] + bb[2 * p], v1 = v[2 * p + 1] + bb[2 * p + 1];
          hs[2 * p]     = f2bf(v0 * cs.x - v1 * cs.y);
          hs[2 * p + 1] = f2bf(v0 * cs.y + v1 * cs.x);
        }
        Cp = (ushort_t*)C1 + (size_t)grow * DM_ + gcol;
      } else if (gcol < DM_ + DK_) {  // K: RoPE
        const int c = gcol - DM_;
        const float2* tp = tab + (size_t)s * 64 + (c >> 1);
        const float* bb = b2 + c;
#pragma unroll
        for (int p = 0; p < 8; ++p) {
          float2 cs = tp[p];
          float v0 = v[2 * p] + bb[2 * p], v1 = v[2 * p + 1] + bb[2 * p + 1];
          hs[2 * p]     = f2bf(v0 * cs.x - v1 * cs.y);
          hs[2 * p + 1] = f2bf(v0 * cs.y + v1 * cs.x);
        }
        Cp = (ushort_t*)C2 + (size_t)grow * DK_ + c;
      } else {                        // V: plain bias
        const int c = gcol - DM_ - DK_;
#pragma unroll
        for (int kk = 0; kk < 16; ++kk) hs[kk] = f2bf(v[kk] + b3[c + kk]);
        Cp = (ushort_t*)C3 + (size_t)grow * DK_ + c;
      }
      uint4 u0, u1;
      u0.x = (uint_t)hs[0] | ((uint_t)hs[1] << 16);
      u0.y = (uint_t)hs[2] | ((uint_t)hs[3] << 16);
      u0.z = (uint_t)hs[4] | ((uint_t)hs[5] << 16);
      u0.w = (uint_t)hs[6] | ((uint_t)hs[7] << 16);
      u1.x = (uint_t)hs[8] | ((uint_t)hs[9] << 16);
      u1.y = (uint_t)hs[10] | ((uint_t)hs[11] << 16);
      u1.z = (uint_t)hs[12] | ((uint_t)hs[13] << 16);
      u1.w = (uint_t)hs[14] | ((uint_t)hs[15] << 16);
      ((uint4*)Cp)[0] = u0;
      ((uint4*)Cp)[1] = u1;
    }
  }
}

// ---------------------------------------------------------------------------
// Causal MQA flash attention v7: 32x32x16 MFMA, in-register P, balanced
// A/B waves, 128-kv macro-staging, exp2-domain softmax + T13 defer-max.
// ---------------------------------------------------------------------------
__global__ __launch_bounds__(512) void attn_mfma7_k(
    const ushort_t* __restrict__ Q, const ushort_t* __restrict__ K,
    const ushort_t* __restrict__ Vt, ushort_t* __restrict__ O) {
  __shared__ ushort_t Ksh[128][136];   // [kv][d]
  __shared__ ushort_t Vsh[128][136];   // [d][kv] (V^T), kv = 128 per macro

  const int bx = blockIdx.x;          // 0..31
  const int hg = blockIdx.y, b = blockIdx.z;
  const int tid = threadIdx.x;
  const int w = tid >> 6, lane = tid & 63;
  const int lq = lane & 31, hi = lane >> 5;
  const int h = hg * 4 + (w & 3);
  const int qt = (w < 4) ? bx : (63 - bx);
  const int q0 = qt * 32;
  const int qg = q0 + lq;
  const int nt = (qt >> 1) + 1;                 // 64-kv steps this wave
  const int ntB = ((63 - bx) >> 1) + 1;         // max 64-kv steps in block
  const int nT = (ntB + 1) >> 1;                // 128-kv macro steps
  const size_t bS = (size_t)b * S_;

  bf16x8 qf[8];
  {
    const ushort_t* qp = Q + (bS + qg) * DM_ + h * DK_ + hi * 8;
#pragma unroll
    for (int kg = 0; kg < 8; ++kg) qf[kg] = *(const bf16x8*)(qp + kg * 16);
  }

  f32x16 oacc[4];
#pragma unroll
  for (int dt = 0; dt < 4; ++dt)
#pragma unroll
    for (int i = 0; i < 16; ++i) oacc[dt][i] = 0.f;
  float m = -INFINITY, l = 0.f;

  bf16x8 kreg[4], vreg[4];
#define ISSUE_LOADS(T0)                                                      \
  {                                                                          \
    const int kv_ = (T0) * 128;                                              \
    _Pragma("unroll") for (int i = 0; i < 4; ++i) {                          \
      int u = tid + i * 512;                                                 \
      kreg[i] = *(const bf16x8*)(K + (bS + kv_ + (u >> 4)) * DK_ + (u & 15) * 8); \
      vreg[i] = *(const bf16x8*)(Vt + ((size_t)b * DK_ + (u >> 4)) * S_ + kv_ + (u & 15) * 8); \
    }                                                                        \
  }

  ISSUE_LOADS(0);

  for (int T = 0; T < nT; ++T) {
    __syncthreads();  // previous macro-tile's LDS reads done
#pragma unroll
    for (int i = 0; i < 4; ++i) {
      int u = tid + i * 512;
      *(bf16x8*)&Ksh[u >> 4][(u & 15) * 8] = kreg[i];
      *(bf16x8*)&Vsh[u >> 4][(u & 15) * 8] = vreg[i];
    }
    if (T + 1 < nT) ISSUE_LOADS(T + 1);
    __syncthreads();  // macro-tile staged

#pragma unroll
    for (int hf = 0; hf < 2; ++hf) {
      const int s64 = 2 * T + hf;
      if (s64 < nt) {
        const int kv0 = s64 * 64;
        const int ko = hf * 64;

        // ---- QK^T: st[kt] = S^T 32x32 tile
        f32x16 st[2];
#pragma unroll
        for (int kt = 0; kt < 2; ++kt)
#pragma unroll
          for (int i = 0; i < 16; ++i) st[kt][i] = 0.f;
        __builtin_amdgcn_s_setprio(1);
#pragma unroll
        for (int kg = 0; kg < 8; ++kg) {
          bf16x8 kf0 = *(const bf16x8*)&Ksh[ko + lq][kg * 16 + hi * 8];
          bf16x8 kf1 = *(const bf16x8*)&Ksh[ko + 32 + lq][kg * 16 + hi * 8];
          st[0] = __builtin_amdgcn_mfma_f32_32x32x16_bf16(kf0, qf[kg], st[0], 0, 0, 0);
          st[1] = __builtin_amdgcn_mfma_f32_32x32x16_bf16(kf1, qf[kg], st[1], 0, 0, 0);
        }
        __builtin_amdgcn_s_setprio(0);

        // ---- online softmax (base-2 domain)
        const float SCL2 = 0.1275174348767325f;  // (1/sqrt(128)) * log2(e)
        const bool need_mask = (kv0 + 63) > q0;
        float tmax = -INFINITY;
#pragma unroll
        for (int kt = 0; kt < 2; ++kt)
#pragma unroll
          for (int r = 0; r < 16; ++r) {
            float s = st[kt][r] * SCL2;
            if (need_mask) {
              int kvi = kv0 + kt * 32 + (r & 3) + 8 * (r >> 2) + 4 * hi;
              if (kvi > qg) s = -INFINITY;
            }
            st[kt][r] = s;
            tmax = fmaxf(tmax, s);
          }
        tmax = fmaxf(tmax, __shfl_xor(tmax, 32));
        if (__any(tmax > m + 8.f)) {  // T13 defer-max
          float mnew = fmaxf(m, tmax);
          float corr = exp2_fast(m - mnew);  // first tile: 2^-inf = 0
          l *= corr;
#pragma unroll
          for (int dt = 0; dt < 4; ++dt)
#pragma unroll
            for (int i = 0; i < 16; ++i) oacc[dt][i] *= corr;
          m = mnew;
        }
        float psum = 0.f;
#pragma unroll
        for (int kt = 0; kt < 2; ++kt)
#pragma unroll
          for (int r = 0; r < 16; ++r) {
            float p = exp2_fast(st[kt][r] - m);  // bounded by 2^8
            st[kt][r] = p;
            psum += p;
          }
        psum += __shfl_xor(psum, 32);
        l += psum;

        // ---- P -> PV B-frags in-register
        uint_t wn[2][4][2], wp[2][4][2];
#pragma unroll
        for (int kt = 0; kt < 2; ++kt)
#pragma unroll
          for (int rb = 0; rb < 4; ++rb)
#pragma unroll
            for (int p = 0; p < 2; ++p) {
              wn[kt][rb][p] = cvt_pk_bf16(st[kt][4 * rb + 2 * p],
                                          st[kt][4 * rb + 2 * p + 1]);
              wp[kt][rb][p] = (uint_t)__shfl_xor((int)wn[kt][rb][p], 32);
            }
        bf16x8 pf[4];
#pragma unroll
        for (int ks = 0; ks < 4; ++ks) {
          const int kt = ks >> 1, rb = 2 * (ks & 1);
          uint4 u;
          u.x = hi ? wp[kt][rb + 1][0] : wn[kt][rb][0];
          u.y = hi ? wp[kt][rb + 1][1] : wn[kt][rb][1];
          u.z = hi ? wn[kt][rb + 1][0] : wp[kt][rb][0];
          u.w = hi ? wn[kt][rb + 1][1] : wp[kt][rb][1];
          pf[ks] = *(bf16x8*)&u;
        }

        // ---- PV: O^T += V^T · P^T
        __builtin_amdgcn_s_setprio(1);
#pragma unroll
        for (int dt = 0; dt < 4; ++dt)
#pragma unroll
          for (int ks = 0; ks < 4; ++ks) {
            bf16x8 vf = *(const bf16x8*)&Vsh[dt * 32 + lq][ko + ks * 16 + hi * 8];
            oacc[dt] = __builtin_amdgcn_mfma_f32_32x32x16_bf16(vf, pf[ks], oacc[dt], 0, 0, 0);
          }
        __builtin_amdgcn_s_setprio(0);
      }
    }
  }
#undef ISSUE_LOADS

  // ---- epilogue: lane q = qg; d = dt*32 + 8*rb + 4*hi + (0..3)
  const float invl = 1.0f / l;
  ushort_t* op = O + (bS + qg) * DM_ + h * DK_;
#pragma unroll
  for (int dt = 0; dt < 4; ++dt)
#pragma unroll
    for (int rb = 0; rb < 4; ++rb) {
      uint2 pk;
      pk.x = cvt_pk_bf16(oacc[dt][4 * rb + 0] * invl,
                         oacc[dt][4 * rb + 1] * invl);
      pk.y = cvt_pk_bf16(oacc[dt][4 * rb + 2] * invl,
                         oacc[dt][4 * rb + 3] * invl);
      *(uint2*)(op + dt * 32 + 8 * rb + 4 * hi) = pk;
    }
}

// ---------------------------------------------------------------------------
extern "C" void kernel_launch(void* const* d_in, const int* in_sizes, int n_in,
                              void* d_out, int out_size, void* d_ws,
                              size_t ws_size, hipStream_t stream) {
  const float* x  = (const float*)d_in[0];
  const int*   tp = (const int*)d_in[1];
  const float* Wq = (const float*)d_in[2];
  const float* bq = (const float*)d_in[3];
  const float* Wk = (const float*)d_in[4];
  const float* bk = (const float*)d_in[5];
  const float* Wv = (const float*)d_in[6];
  const float* bv = (const float*)d_in[7];
  const float* Wo = (const float*)d_in[8];
  const float* bo = (const float*)d_in[9];
  float* out = (float*)d_out;

  const int NQKV = DM_ + 2 * DK_;  // 2304
  ushort_t* WqkvT = (ushort_t*)d_ws;                    // 2304*DM  9.5 MB
  ushort_t* WoT   = WqkvT + (size_t)NQKV * DM_;         // DM*DM    8 MB
  ushort_t* Qbf   = WoT + (size_t)DM_ * DM_;            // M*DM     16 MB
  ushort_t* Kbf   = Qbf + (size_t)M_ * DM_;             // M*DK     1 MB
  ushort_t* Vbf   = Kbf + (size_t)M_ * DK_;             // M*DK     1 MB
  ushort_t* Vtb   = Vbf + (size_t)M_ * DK_;             // B*DK*S   1 MB
  float2*   tab   = (float2*)(Vtb + (size_t)M_ * DK_);  // S*64     1 MB
  ushort_t* ATb   = (ushort_t*)(tab + (size_t)S_ * 64); // M*DM     16 MB

  tconv_k<<<dim3(DM_ / 64, DM_ / 64), 256, 0, stream>>>(Wq, WqkvT, DM_, DM_);
  tconv_k<<<dim3(DK_ / 64, DM_ / 64), 256, 0, stream>>>(
      Wk, WqkvT + (size_t)DM_ * DM_, DM_, DK_);
  tconv_k<<<dim3(DK_ / 64, DM_ / 64), 256, 0, stream>>>(
      Wv, WqkvT + (size_t)(DM_ + DK_) * DM_, DM_, DK_);
  tconv_k<<<dim3(DM_ / 64, DM_ / 64), 256, 0, stream>>>(Wo, WoT, DM_, DM_);
  rope_tab_k<<<S_ * 64 / 256, 256, 0, stream>>>(tp, tab);

  // Fused QKV projection (MFMA; fp32 A converted in-staging; Q,K get RoPE)
  gemm_mfma_k<1, 1><<<dim3(NQKV / 128, M_ / 128), 256, 0, stream>>>(
      (const void*)x, WqkvT, bq, bk, bv, tab, (void*)Qbf, (void*)Kbf,
      (void*)Vbf, NQKV, DM_);

  // V -> V^T per batch
  vtrans_k<<<dim3(S_ / 64, DK_ / 64, B_), 256, 0, stream>>>(Vbf, Vtb);

  // Causal MQA attention v7 (exp2 softmax, defer-max, 128-kv macro-stage)
  attn_mfma7_k<<<dim3(S_ / 64, H_ / 4, B_), 512, 0, stream>>>(
      Qbf, Kbf, Vtb, ATb);

  // Output projection (MFMA, fp32 out)
  gemm_mfma_k<0, 0><<<dim3(DM_ / 128, M_ / 128), 256, 0, stream>>>(
      (const void*)ATb, WoT, bo, nullptr, nullptr, nullptr, (void*)out,
      nullptr, nullptr, DM_, DM_);
}

// Round 14
// 214.890 us; speedup vs baseline: 1.0793x; 1.0314x over previous
//
#include <hip/hip_runtime.h>
#include <math.h>

#define B_  2
#define S_  2048
#define DM_ 2048
#define H_  16
#define DK_ 128
#define M_  (B_ * S_)

typedef __attribute__((ext_vector_type(8))) short bf16x8;
typedef __attribute__((ext_vector_type(4))) float f32x4;
typedef __attribute__((ext_vector_type(16))) float f32x16;
typedef unsigned short ushort_t;
typedef unsigned int uint_t;

__device__ inline ushort_t f2bf(float f) {
  union { float f; uint_t u; } v; v.f = f;
  uint_t u = v.u;
  uint_t r = (u + 0x7FFFu + ((u >> 16) & 1u)) >> 16;  // RNE
  return (ushort_t)r;
}

__device__ __forceinline__ uint_t cvt_pk_bf16(float a, float b) {
  uint_t r;
  asm("v_cvt_pk_bf16_f32 %0, %1, %2" : "=v"(r) : "v"(a), "v"(b));
  return r;  // lo16 = bf16(a), hi16 = bf16(b)
}

__device__ __forceinline__ float exp2_fast(float x) {
  float r;
  asm("v_exp_f32 %0, %1" : "=v"(r) : "v"(x));
  return r;  // 2^x
}

#define SBAR()                                   \
  {                                              \
    __builtin_amdgcn_sched_barrier(0);           \
    __builtin_amdgcn_s_barrier();                \
    __builtin_amdgcn_sched_barrier(0);           \
  }
#define VMCNT(n) asm volatile("s_waitcnt vmcnt(" #n ")" ::: "memory")
#define LGKM0()                                          \
  {                                                      \
    asm volatile("s_waitcnt lgkmcnt(0)" ::: "memory");   \
    __builtin_amdgcn_sched_barrier(0);                   \
  }

// ---------------------------------------------------------------------------
// fp32 -> bf16 elementwise convert
// ---------------------------------------------------------------------------
__global__ void cvt_bf16_k(const float* __restrict__ in,
                           ushort_t* __restrict__ out, int n) {
  int i = (blockIdx.x * 256 + threadIdx.x) * 4;
  if (i >= n) return;
  float4 v = *(const float4*)(in + i);
  uint2 pk;
  pk.x = cvt_pk_bf16(v.x, v.y);
  pk.y = cvt_pk_bf16(v.z, v.w);
  *(uint2*)(out + i) = pk;
}

// ---------------------------------------------------------------------------
// RoPE table: tab[s*64 + i] = (cos, sin) of pos[s] * 10000^(-i/64)
// ---------------------------------------------------------------------------
__global__ void rope_tab_k(const int* __restrict__ pos,
                           float2* __restrict__ tab) {
  int idx = blockIdx.x * 256 + threadIdx.x;
  int s = idx >> 6, i = idx & 63;
  float ang = (float)pos[s] * exp2f((float)i * -0.2076205059304601f);
  float sn, cs;
  sincosf(ang, &sn, &cs);
  tab[idx] = make_float2(cs, sn);
}

// ---------------------------------------------------------------------------
// fp32 [K][N] -> bf16 [N][K] tiled transpose-convert (64x64 tiles)
// ---------------------------------------------------------------------------
__global__ __launch_bounds__(256) void tconv_k(const float* __restrict__ W,
                                               ushort_t* __restrict__ WT,
                                               int K, int N) {
  __shared__ ushort_t Ls[64][72];
  const int k0 = blockIdx.y * 64, n0 = blockIdx.x * 64;
  const int t = threadIdx.x;
  const int r = t >> 4, c4 = t & 15;
#pragma unroll
  for (int i = 0; i < 4; ++i) {
    int row = r + i * 16;
    float4 v = *(const float4*)(W + (size_t)(k0 + row) * N + n0 + c4 * 4);
    Ls[row][c4 * 4 + 0] = f2bf(v.x);
    Ls[row][c4 * 4 + 1] = f2bf(v.y);
    Ls[row][c4 * 4 + 2] = f2bf(v.z);
    Ls[row][c4 * 4 + 3] = f2bf(v.w);
  }
  __syncthreads();
#pragma unroll
  for (int i = 0; i < 4; ++i) {
    int chunk = t + i * 256;
    int nr = chunk >> 4, kc = chunk & 15;
    uint2 pk;
    pk.x = (uint_t)Ls[kc * 4 + 0][nr] | ((uint_t)Ls[kc * 4 + 1][nr] << 16);
    pk.y = (uint_t)Ls[kc * 4 + 2][nr] | ((uint_t)Ls[kc * 4 + 3][nr] << 16);
    *(uint2*)(WT + (size_t)(n0 + nr) * K + k0 + kc * 4) = pk;
  }
}

// ---------------------------------------------------------------------------
// bf16 [b*S+s][128] -> bf16 [b][128][S] transpose (per-batch V^T)
// ---------------------------------------------------------------------------
__global__ __launch_bounds__(256) void vtrans_k(const ushort_t* __restrict__ Vb,
                                                ushort_t* __restrict__ Vt) {
  __shared__ ushort_t Ls[64][72];
  const int s0 = blockIdx.x * 64, d0 = blockIdx.y * 64, b = blockIdx.z;
  const int t = threadIdx.x;
#pragma unroll
  for (int i = 0; i < 2; ++i) {
    int c = t + i * 256;
    int row = c >> 3, c8 = c & 7;
    *(bf16x8*)&Ls[row][c8 * 8] =
        *(const bf16x8*)(Vb + ((size_t)b * S_ + s0 + row) * DK_ + d0 + c8 * 8);
  }
  __syncthreads();
#pragma unroll
  for (int i = 0; i < 2; ++i) {
    int c = t + i * 256;
    int dr = c >> 3, s8 = c & 7;
    uint4 pk;
    pk.x = (uint_t)Ls[s8 * 8 + 0][dr] | ((uint_t)Ls[s8 * 8 + 1][dr] << 16);
    pk.y = (uint_t)Ls[s8 * 8 + 2][dr] | ((uint_t)Ls[s8 * 8 + 3][dr] << 16);
    pk.z = (uint_t)Ls[s8 * 8 + 4][dr] | ((uint_t)Ls[s8 * 8 + 5][dr] << 16);
    pk.w = (uint_t)Ls[s8 * 8 + 6][dr] | ((uint_t)Ls[s8 * 8 + 7][dr] << 16);
    *(uint4*)(Vt + ((size_t)b * DK_ + d0 + dr) * S_ + s0 + s8 * 8) = pk;
  }
}

// ---------------------------------------------------------------------------
// Counted-vmcnt bf16 MFMA GEMM (T3+T4 minimum): C = A @ Bt^T + bias.
// BM=256, BN=128, BK=64; 8 waves (2M x 4N), wave-tile 128x32.
// Ring-2 K-tile slots (96 KB LDS). Per K-tile:
//   VMCNT(6) -> s_barrier -> 64 MFMA/wave -> s_barrier -> stage slot<-kt+2.
// vmcnt(6) (never 0 in the loop) keeps the other slot's 6 loads in flight.
// T2 swizzle: chunk ^= (row&7), pre-swizzled GLOBAL source + swizzled
// ds_read, linear LDS dest (rule #21).
// EPI: 0 = fp32 out + bias b1; 1 = fused QKV routing (Q RoPE / K RoPE / V).
// ---------------------------------------------------------------------------
template <int EPI>
__global__ __launch_bounds__(512, 2) void gemm8_k(
    const ushort_t* __restrict__ A, const ushort_t* __restrict__ Bt,
    const float* __restrict__ b1, const float* __restrict__ b2,
    const float* __restrict__ b3, const float2* __restrict__ tab,
    void* __restrict__ C1, void* __restrict__ C2, void* __restrict__ C3,
    int N, int K) {
  __shared__ ushort_t LDS[49152];  // 96 KB
  ushort_t* As0 = LDS;             // [256][64] per slot
  ushort_t* As1 = LDS + 16384;
  ushort_t* Bs0 = LDS + 32768;     // [128][64] per slot
  ushort_t* Bs1 = LDS + 40960;

  const int nwg = gridDim.x * gridDim.y;
  const int orig = blockIdx.y * gridDim.x + blockIdx.x;
  const int qq = nwg >> 3;
  const int swz = (orig & 7) * qq + (orig >> 3);
  const int bx = swz % gridDim.x, by = swz / gridDim.x;

  const int tid = threadIdx.x;
  const int lane = tid & 63;
  const int lr = lane & 15, lg = lane >> 4;
  const int w = tid >> 6, wm = w >> 2, wn = w & 3;
  const int row0 = by * 256, col0 = bx * 128;

  f32x4 acc[8][2];
#pragma unroll
  for (int i = 0; i < 8; ++i)
#pragma unroll
    for (int j = 0; j < 2; ++j) acc[i][j] = (f32x4){0.f, 0.f, 0.f, 0.f};

#define STAGE(ASL, BSL, KT)                                                  \
  {                                                                          \
    _Pragma("unroll") for (int i = 0; i < 4; ++i) {                          \
      int u = tid + i * 512;                                                 \
      int r = u >> 3, ch = u & 7;                                            \
      int gch = ch ^ (r & 7);                                                \
      __builtin_amdgcn_global_load_lds(                                      \
          (const __attribute__((address_space(1))) void*)(                   \
              A + (size_t)(row0 + r) * K + (KT) * 64 + gch * 8),             \
          (__attribute__((address_space(3))) void*)((ASL) + u * 8), 16, 0, 0); \
    }                                                                        \
    _Pragma("unroll") for (int i = 0; i < 2; ++i) {                          \
      int u = tid + i * 512;                                                 \
      int r = u >> 3, ch = u & 7;                                            \
      int gch = ch ^ (r & 7);                                                \
      __builtin_amdgcn_global_load_lds(                                      \
          (const __attribute__((address_space(1))) void*)(                   \
              Bt + (size_t)(col0 + r) * K + (KT) * 64 + gch * 8),            \
          (__attribute__((address_space(3))) void*)((BSL) + u * 8), 16, 0, 0); \
    }                                                                        \
  }

  const int nkt = K >> 6;  // K-tiles of 64
  // prologue: fill both slots
  STAGE(As0, Bs0, 0);
  STAGE(As1, Bs1, 1);

  for (int kt = 0; kt < nkt; ++kt) {
    const int sl = kt & 1;
    const ushort_t* as = sl ? As1 : As0;
    const ushort_t* bs = sl ? Bs1 : Bs0;
    ushort_t* asw = sl ? As1 : As0;
    ushort_t* bsw = sl ? Bs1 : Bs0;

    if (kt + 2 < nkt) { VMCNT(6); } else { VMCNT(0); }
    SBAR();  // slot sl visible to all waves

#pragma unroll
    for (int ki = 0; ki < 2; ++ki) {
      bf16x8 af[8], bfr[2];
#pragma unroll
      for (int mi = 0; mi < 8; ++mi) {
        int r = wm * 128 + mi * 16 + lr;
        int sch = (ki * 4 + lg) ^ (r & 7);
        af[mi] = *(const bf16x8*)&as[r * 64 + sch * 8];
      }
#pragma unroll
      for (int ni = 0; ni < 2; ++ni) {
        int r = wn * 32 + ni * 16 + lr;
        int sch = (ki * 4 + lg) ^ (r & 7);
        bfr[ni] = *(const bf16x8*)&bs[r * 64 + sch * 8];
      }
#pragma unroll
      for (int mi = 0; mi < 8; ++mi)
#pragma unroll
        for (int ni = 0; ni < 2; ++ni)
          acc[mi][ni] = __builtin_amdgcn_mfma_f32_16x16x32_bf16(
              af[mi], bfr[ni], acc[mi][ni], 0, 0, 0);
    }
    SBAR();  // all waves done reading slot sl
    if (kt + 2 < nkt) STAGE(asw, bsw, kt + 2);
  }
#undef STAGE

  // ---- epilogue: per-wave private LDS restage (no cross-wave barrier)
  float* Ep = (float*)LDS + w * (16 * 36);  // 16 rows x 36 (pad) f32
  const int er = lane >> 2;                 // 0..15
  const int ec = (lane & 3) * 8;            // 0..24
  const int gcol = col0 + wn * 32 + ec;

#pragma unroll
  for (int mi = 0; mi < 8; ++mi) {
#pragma unroll
    for (int ni = 0; ni < 2; ++ni)
#pragma unroll
      for (int j = 0; j < 4; ++j)
        Ep[(lg * 4 + j) * 36 + ni * 16 + lr] = acc[mi][ni][j];
    LGKM0();

    const int grow = row0 + wm * 128 + mi * 16 + er;
    float v[8];
    *(float4*)(v)     = *(const float4*)&Ep[er * 36 + ec];
    *(float4*)(v + 4) = *(const float4*)&Ep[er * 36 + ec + 4];
    LGKM0();  // reads complete before next mi's writes

    if (EPI == 0) {
      float* Cp = (float*)C1 + (size_t)grow * N + gcol;
      float4 bb0 = *(const float4*)&b1[gcol];
      float4 bb1 = *(const float4*)&b1[gcol + 4];
      float4 o0, o1;
      o0.x = v[0] + bb0.x; o0.y = v[1] + bb0.y;
      o0.z = v[2] + bb0.z; o0.w = v[3] + bb0.w;
      o1.x = v[4] + bb1.x; o1.y = v[5] + bb1.y;
      o1.z = v[6] + bb1.z; o1.w = v[7] + bb1.w;
      *(float4*)Cp = o0;
      *(float4*)(Cp + 4) = o1;
    } else {
      const int s = grow & (S_ - 1);
      ushort_t hs[8];
      ushort_t* Cp;
      if (gcol < DM_) {               // Q: RoPE
        const float2* tp = tab + (size_t)s * 64 + ((gcol & 127) >> 1);
        const float* bb = b1 + gcol;
#pragma unroll
        for (int p = 0; p < 4; ++p) {
          float2 cs = tp[p];
          float v0 = v[2 * p] + bb[2 * p], v1 = v[2 * p + 1] + bb[2 * p + 1];
          hs[2 * p]     = f2bf(v0 * cs.x - v1 * cs.y);
          hs[2 * p + 1] = f2bf(v0 * cs.y + v1 * cs.x);
        }
        Cp = (ushort_t*)C1 + (size_t)grow * DM_ + gcol;
      } else if (gcol < DM_ + DK_) {  // K: RoPE
        const int c = gcol - DM_;
        const float2* tp = tab + (size_t)s * 64 + (c >> 1);
        const float* bb = b2 + c;
#pragma unroll
        for (int p = 0; p < 4; ++p) {
          float2 cs = tp[p];
          float v0 = v[2 * p] + bb[2 * p], v1 = v[2 * p + 1] + bb[2 * p + 1];
          hs[2 * p]     = f2bf(v0 * cs.x - v1 * cs.y);
          hs[2 * p + 1] = f2bf(v0 * cs.y + v1 * cs.x);
        }
        Cp = (ushort_t*)C2 + (size_t)grow * DK_ + c;
      } else {                        // V: plain bias
        const int c = gcol - DM_ - DK_;
#pragma unroll
        for (int kk = 0; kk < 8; ++kk) hs[kk] = f2bf(v[kk] + b3[c + kk]);
        Cp = (ushort_t*)C3 + (size_t)grow * DK_ + c;
      }
      uint4 u0;
      u0.x = (uint_t)hs[0] | ((uint_t)hs[1] << 16);
      u0.y = (uint_t)hs[2] | ((uint_t)hs[3] << 16);
      u0.z = (uint_t)hs[4] | ((uint_t)hs[5] << 16);
      u0.w = (uint_t)hs[6] | ((uint_t)hs[7] << 16);
      *(uint4*)Cp = u0;
    }
  }
}

// ---------------------------------------------------------------------------
// Causal MQA flash attention v7: 32x32x16 MFMA, in-register P, balanced
// A/B waves, 128-kv macro-staging, exp2-domain softmax + T13 defer-max.
// ---------------------------------------------------------------------------
__global__ __launch_bounds__(512) void attn_mfma7_k(
    const ushort_t* __restrict__ Q, const ushort_t* __restrict__ K,
    const ushort_t* __restrict__ Vt, ushort_t* __restrict__ O) {
  __shared__ ushort_t Ksh[128][136];   // [kv][d]
  __shared__ ushort_t Vsh[128][136];   // [d][kv] (V^T), kv = 128 per macro

  const int bx = blockIdx.x;          // 0..31
  const int hg = blockIdx.y, b = blockIdx.z;
  const int tid = threadIdx.x;
  const int w = tid >> 6, lane = tid & 63;
  const int lq = lane & 31, hi = lane >> 5;
  const int h = hg * 4 + (w & 3);
  const int qt = (w < 4) ? bx : (63 - bx);
  const int q0 = qt * 32;
  const int qg = q0 + lq;
  const int nt = (qt >> 1) + 1;                 // 64-kv steps this wave
  const int ntB = ((63 - bx) >> 1) + 1;         // max 64-kv steps in block
  const int nT = (ntB + 1) >> 1;                // 128-kv macro steps
  const size_t bS = (size_t)b * S_;

  bf16x8 qf[8];
  {
    const ushort_t* qp = Q + (bS + qg) * DM_ + h * DK_ + hi * 8;
#pragma unroll
    for (int kg = 0; kg < 8; ++kg) qf[kg] = *(const bf16x8*)(qp + kg * 16);
  }

  f32x16 oacc[4];
#pragma unroll
  for (int dt = 0; dt < 4; ++dt)
#pragma unroll
    for (int i = 0; i < 16; ++i) oacc[dt][i] = 0.f;
  float m = -INFINITY, l = 0.f;

  bf16x8 kreg[4], vreg[4];
#define ISSUE_LOADS(T0)                                                      \
  {                                                                          \
    const int kv_ = (T0) * 128;                                              \
    _Pragma("unroll") for (int i = 0; i < 4; ++i) {                          \
      int u = tid + i * 512;                                                 \
      kreg[i] = *(const bf16x8*)(K + (bS + kv_ + (u >> 4)) * DK_ + (u & 15) * 8); \
      vreg[i] = *(const bf16x8*)(Vt + ((size_t)b * DK_ + (u >> 4)) * S_ + kv_ + (u & 15) * 8); \
    }                                                                        \
  }

  ISSUE_LOADS(0);

  for (int T = 0; T < nT; ++T) {
    __syncthreads();  // previous macro-tile's LDS reads done
#pragma unroll
    for (int i = 0; i < 4; ++i) {
      int u = tid + i * 512;
      *(bf16x8*)&Ksh[u >> 4][(u & 15) * 8] = kreg[i];
      *(bf16x8*)&Vsh[u >> 4][(u & 15) * 8] = vreg[i];
    }
    if (T + 1 < nT) ISSUE_LOADS(T + 1);
    __syncthreads();  // macro-tile staged

#pragma unroll
    for (int hf = 0; hf < 2; ++hf) {
      const int s64 = 2 * T + hf;
      if (s64 < nt) {
        const int kv0 = s64 * 64;
        const int ko = hf * 64;

        f32x16 st[2];
#pragma unroll
        for (int kt = 0; kt < 2; ++kt)
#pragma unroll
          for (int i = 0; i < 16; ++i) st[kt][i] = 0.f;
        __builtin_amdgcn_s_setprio(1);
#pragma unroll
        for (int kg = 0; kg < 8; ++kg) {
          bf16x8 kf0 = *(const bf16x8*)&Ksh[ko + lq][kg * 16 + hi * 8];
          bf16x8 kf1 = *(const bf16x8*)&Ksh[ko + 32 + lq][kg * 16 + hi * 8];
          st[0] = __builtin_amdgcn_mfma_f32_32x32x16_bf16(kf0, qf[kg], st[0], 0, 0, 0);
          st[1] = __builtin_amdgcn_mfma_f32_32x32x16_bf16(kf1, qf[kg], st[1], 0, 0, 0);
        }
        __builtin_amdgcn_s_setprio(0);

        const float SCL2 = 0.1275174348767325f;  // (1/sqrt(128)) * log2(e)
        const bool need_mask = (kv0 + 63) > q0;
        float tmax = -INFINITY;
#pragma unroll
        for (int kt = 0; kt < 2; ++kt)
#pragma unroll
          for (int r = 0; r < 16; ++r) {
            float s = st[kt][r] * SCL2;
            if (need_mask) {
              int kvi = kv0 + kt * 32 + (r & 3) + 8 * (r >> 2) + 4 * hi;
              if (kvi > qg) s = -INFINITY;
            }
            st[kt][r] = s;
            tmax = fmaxf(tmax, s);
          }
        tmax = fmaxf(tmax, __shfl_xor(tmax, 32));
        if (__any(tmax > m + 8.f)) {  // T13 defer-max
          float mnew = fmaxf(m, tmax);
          float corr = exp2_fast(m - mnew);
          l *= corr;
#pragma unroll
          for (int dt = 0; dt < 4; ++dt)
#pragma unroll
            for (int i = 0; i < 16; ++i) oacc[dt][i] *= corr;
          m = mnew;
        }
        float psum = 0.f;
#pragma unroll
        for (int kt = 0; kt < 2; ++kt)
#pragma unroll
          for (int r = 0; r < 16; ++r) {
            float p = exp2_fast(st[kt][r] - m);
            st[kt][r] = p;
            psum += p;
          }
        psum += __shfl_xor(psum, 32);
        l += psum;

        uint_t wn2[2][4][2], wp2[2][4][2];
#pragma unroll
        for (int kt = 0; kt < 2; ++kt)
#pragma unroll
          for (int rb = 0; rb < 4; ++rb)
#pragma unroll
            for (int p = 0; p < 2; ++p) {
              wn2[kt][rb][p] = cvt_pk_bf16(st[kt][4 * rb + 2 * p],
                                           st[kt][4 * rb + 2 * p + 1]);
              wp2[kt][rb][p] = (uint_t)__shfl_xor((int)wn2[kt][rb][p], 32);
            }
        bf16x8 pf[4];
#pragma unroll
        for (int ks = 0; ks < 4; ++ks) {
          const int kt = ks >> 1, rb = 2 * (ks & 1);
          uint4 u;
          u.x = hi ? wp2[kt][rb + 1][0] : wn2[kt][rb][0];
          u.y = hi ? wp2[kt][rb + 1][1] : wn2[kt][rb][1];
          u.z = hi ? wn2[kt][rb + 1][0] : wp2[kt][rb][0];
          u.w = hi ? wn2[kt][rb + 1][1] : wp2[kt][rb][1];
          pf[ks] = *(bf16x8*)&u;
        }

        __builtin_amdgcn_s_setprio(1);
#pragma unroll
        for (int dt = 0; dt < 4; ++dt)
#pragma unroll
          for (int ks = 0; ks < 4; ++ks) {
            bf16x8 vf = *(const bf16x8*)&Vsh[dt * 32 + lq][ko + ks * 16 + hi * 8];
            oacc[dt] = __builtin_amdgcn_mfma_f32_32x32x16_bf16(vf, pf[ks], oacc[dt], 0, 0, 0);
          }
        __builtin_amdgcn_s_setprio(0);
      }
    }
  }
#undef ISSUE_LOADS

  const float invl = 1.0f / l;
  ushort_t* op = O + (bS + qg) * DM_ + h * DK_;
#pragma unroll
  for (int dt = 0; dt < 4; ++dt)
#pragma unroll
    for (int rb = 0; rb < 4; ++rb) {
      uint2 pk;
      pk.x = cvt_pk_bf16(oacc[dt][4 * rb + 0] * invl,
                         oacc[dt][4 * rb + 1] * invl);
      pk.y = cvt_pk_bf16(oacc[dt][4 * rb + 2] * invl,
                         oacc[dt][4 * rb + 3] * invl);
      *(uint2*)(op + dt * 32 + 8 * rb + 4 * hi) = pk;
    }
}

// ---------------------------------------------------------------------------
extern "C" void kernel_launch(void* const* d_in, const int* in_sizes, int n_in,
                              void* d_out, int out_size, void* d_ws,
                              size_t ws_size, hipStream_t stream) {
  const float* x  = (const float*)d_in[0];
  const int*   tp = (const int*)d_in[1];
  const float* Wq = (const float*)d_in[2];
  const float* bq = (const float*)d_in[3];
  const float* Wk = (const float*)d_in[4];
  const float* bk = (const float*)d_in[5];
  const float* Wv = (const float*)d_in[6];
  const float* bv = (const float*)d_in[7];
  const float* Wo = (const float*)d_in[8];
  const float* bo = (const float*)d_in[9];
  float* out = (float*)d_out;

  const int NQKV = DM_ + 2 * DK_;  // 2304
  ushort_t* Xbf   = (ushort_t*)d_ws;                    // M*DM     16 MB
  ushort_t* WqkvT = Xbf + (size_t)M_ * DM_;             // 2304*DM  9.5 MB
  ushort_t* WoT   = WqkvT + (size_t)NQKV * DM_;         // DM*DM    8 MB
  ushort_t* Qbf   = WoT + (size_t)DM_ * DM_;            // M*DM     16 MB
  ushort_t* Kbf   = Qbf + (size_t)M_ * DM_;             // M*DK     1 MB
  ushort_t* Vbf   = Kbf + (size_t)M_ * DK_;             // M*DK     1 MB
  ushort_t* Vtb   = Vbf + (size_t)M_ * DK_;             // B*DK*S   1 MB
  float2*   tab   = (float2*)(Vtb + (size_t)M_ * DK_);  // S*64     1 MB
  ushort_t* ATb   = Xbf;  // alias: Xbf dead after QKV projection

  cvt_bf16_k<<<(M_ * DM_ / 4 + 255) / 256, 256, 0, stream>>>(x, Xbf, M_ * DM_);
  tconv_k<<<dim3(DM_ / 64, DM_ / 64), 256, 0, stream>>>(Wq, WqkvT, DM_, DM_);
  tconv_k<<<dim3(DK_ / 64, DM_ / 64), 256, 0, stream>>>(
      Wk, WqkvT + (size_t)DM_ * DM_, DM_, DK_);
  tconv_k<<<dim3(DK_ / 64, DM_ / 64), 256, 0, stream>>>(
      Wv, WqkvT + (size_t)(DM_ + DK_) * DM_, DM_, DK_);
  tconv_k<<<dim3(DM_ / 64, DM_ / 64), 256, 0, stream>>>(Wo, WoT, DM_, DM_);
  rope_tab_k<<<S_ * 64 / 256, 256, 0, stream>>>(tp, tab);

  // Fused QKV projection (counted-vmcnt GEMM; Q,K get RoPE; bf16 out)
  gemm8_k<1><<<dim3(NQKV / 128, M_ / 256), 512, 0, stream>>>(
      Xbf, WqkvT, bq, bk, bv, tab, (void*)Qbf, (void*)Kbf, (void*)Vbf,
      NQKV, DM_);

  // V -> V^T per batch
  vtrans_k<<<dim3(S_ / 64, DK_ / 64, B_), 256, 0, stream>>>(Vbf, Vtb);

  // Causal MQA attention v7
  attn_mfma7_k<<<dim3(S_ / 64, H_ / 4, B_), 512, 0, stream>>>(
      Qbf, Kbf, Vtb, ATb);

  // Output projection (counted-vmcnt GEMM, fp32 out)
  gemm8_k<0><<<dim3(DM_ / 128, M_ / 256), 512, 0, stream>>>(
      ATb, WoT, bo, nullptr, nullptr, nullptr, (void*)out, nullptr, nullptr,
      DM_, DM_);
}

// Round 15
// 203.430 us; speedup vs baseline: 1.1401x; 1.0563x over previous
//
#include <hip/hip_runtime.h>
#include <math.h>

#define B_  2
#define S_  2048
#define DM_ 2048
#define H_  16
#define DK_ 128
#define M_  (B_ * S_)

typedef __attribute__((ext_vector_type(8))) short bf16x8;
typedef __attribute__((ext_vector_type(4))) float f32x4;
typedef __attribute__((ext_vector_type(16))) float f32x16;
typedef unsigned short ushort_t;
typedef unsigned int uint_t;

__device__ inline ushort_t f2bf(float f) {
  union { float f; uint_t u; } v; v.f = f;
  uint_t u = v.u;
  uint_t r = (u + 0x7FFFu + ((u >> 16) & 1u)) >> 16;  // RNE
  return (ushort_t)r;
}

__device__ __forceinline__ uint_t cvt_pk_bf16(float a, float b) {
  uint_t r;
  asm("v_cvt_pk_bf16_f32 %0, %1, %2" : "=v"(r) : "v"(a), "v"(b));
  return r;  // lo16 = bf16(a), hi16 = bf16(b)
}

__device__ __forceinline__ float exp2_fast(float x) {
  float r;
  asm("v_exp_f32 %0, %1" : "=v"(r) : "v"(x));
  return r;  // 2^x
}

#define SBAR()                                   \
  {                                              \
    __builtin_amdgcn_sched_barrier(0);           \
    __builtin_amdgcn_s_barrier();                \
    __builtin_amdgcn_sched_barrier(0);           \
  }
#define VMCNT(n) asm volatile("s_waitcnt vmcnt(" #n ")" ::: "memory")
#define LGKM0()                                          \
  {                                                      \
    asm volatile("s_waitcnt lgkmcnt(0)" ::: "memory");   \
    __builtin_amdgcn_sched_barrier(0);                   \
  }

// ---------------------------------------------------------------------------
// fp32 -> bf16 elementwise convert
// ---------------------------------------------------------------------------
__global__ void cvt_bf16_k(const float* __restrict__ in,
                           ushort_t* __restrict__ out, int n) {
  int i = (blockIdx.x * 256 + threadIdx.x) * 4;
  if (i >= n) return;
  float4 v = *(const float4*)(in + i);
  uint2 pk;
  pk.x = cvt_pk_bf16(v.x, v.y);
  pk.y = cvt_pk_bf16(v.z, v.w);
  *(uint2*)(out + i) = pk;
}

// ---------------------------------------------------------------------------
// RoPE table: tab[s*64 + i] = (cos, sin) of pos[s] * 10000^(-i/64)
// ---------------------------------------------------------------------------
__global__ void rope_tab_k(const int* __restrict__ pos,
                           float2* __restrict__ tab) {
  int idx = blockIdx.x * 256 + threadIdx.x;
  int s = idx >> 6, i = idx & 63;
  float ang = (float)pos[s] * exp2f((float)i * -0.2076205059304601f);
  float sn, cs;
  sincosf(ang, &sn, &cs);
  tab[idx] = make_float2(cs, sn);
}

// ---------------------------------------------------------------------------
// fp32 [K][N] -> bf16 [N][K] tiled transpose-convert (64x64 tiles)
// ---------------------------------------------------------------------------
__global__ __launch_bounds__(256) void tconv_k(const float* __restrict__ W,
                                               ushort_t* __restrict__ WT,
                                               int K, int N) {
  __shared__ ushort_t Ls[64][72];
  const int k0 = blockIdx.y * 64, n0 = blockIdx.x * 64;
  const int t = threadIdx.x;
  const int r = t >> 4, c4 = t & 15;
#pragma unroll
  for (int i = 0; i < 4; ++i) {
    int row = r + i * 16;
    float4 v = *(const float4*)(W + (size_t)(k0 + row) * N + n0 + c4 * 4);
    Ls[row][c4 * 4 + 0] = f2bf(v.x);
    Ls[row][c4 * 4 + 1] = f2bf(v.y);
    Ls[row][c4 * 4 + 2] = f2bf(v.z);
    Ls[row][c4 * 4 + 3] = f2bf(v.w);
  }
  __syncthreads();
#pragma unroll
  for (int i = 0; i < 4; ++i) {
    int chunk = t + i * 256;
    int nr = chunk >> 4, kc = chunk & 15;
    uint2 pk;
    pk.x = (uint_t)Ls[kc * 4 + 0][nr] | ((uint_t)Ls[kc * 4 + 1][nr] << 16);
    pk.y = (uint_t)Ls[kc * 4 + 2][nr] | ((uint_t)Ls[kc * 4 + 3][nr] << 16);
    *(uint2*)(WT + (size_t)(n0 + nr) * K + k0 + kc * 4) = pk;
  }
}

// ---------------------------------------------------------------------------
// bf16 [b*S+s][128] -> bf16 [b][128][S] transpose (per-batch V^T)
// ---------------------------------------------------------------------------
__global__ __launch_bounds__(256) void vtrans_k(const ushort_t* __restrict__ Vb,
                                                ushort_t* __restrict__ Vt) {
  __shared__ ushort_t Ls[64][72];
  const int s0 = blockIdx.x * 64, d0 = blockIdx.y * 64, b = blockIdx.z;
  const int t = threadIdx.x;
#pragma unroll
  for (int i = 0; i < 2; ++i) {
    int c = t + i * 256;
    int row = c >> 3, c8 = c & 7;
    *(bf16x8*)&Ls[row][c8 * 8] =
        *(const bf16x8*)(Vb + ((size_t)b * S_ + s0 + row) * DK_ + d0 + c8 * 8);
  }
  __syncthreads();
#pragma unroll
  for (int i = 0; i < 2; ++i) {
    int c = t + i * 256;
    int dr = c >> 3, s8 = c & 7;
    uint4 pk;
    pk.x = (uint_t)Ls[s8 * 8 + 0][dr] | ((uint_t)Ls[s8 * 8 + 1][dr] << 16);
    pk.y = (uint_t)Ls[s8 * 8 + 2][dr] | ((uint_t)Ls[s8 * 8 + 3][dr] << 16);
    pk.z = (uint_t)Ls[s8 * 8 + 4][dr] | ((uint_t)Ls[s8 * 8 + 5][dr] << 16);
    pk.w = (uint_t)Ls[s8 * 8 + 6][dr] | ((uint_t)Ls[s8 * 8 + 7][dr] << 16);
    *(uint4*)(Vt + ((size_t)b * DK_ + d0 + dr) * S_ + s0 + s8 * 8) = pk;
  }
}

// ---------------------------------------------------------------------------
// Counted-vmcnt bf16 MFMA GEMM (T3+T4): C = A @ Bt^T + bias.
// BM=128, BN=128, BK=64; 4 waves (2x2), wave-tile 64x64 (32 flop/LDS-byte).
// Ring-2 K-tile slots, 64 KB LDS -> 2 blocks/CU (cross-block overlap hides
// the per-K-tile barriers). Per K-tile:
//   VMCNT(8) -> s_barrier -> 32 MFMA/wave -> s_barrier -> stage slot<-kt+2.
// 8 loads/thread/K-tile (A 4 + B 4 @ 256 thr), ring-2 -> VMCNT(8) steady.
// T2 swizzle: chunk ^= (row&7), pre-swizzled GLOBAL source + swizzled
// ds_read, linear LDS dest (rule #21). T5 setprio around MFMA cluster.
// EPI: 0 = fp32 out + bias b1; 1 = fused QKV routing (Q RoPE / K RoPE / V).
// ---------------------------------------------------------------------------
template <int EPI>
__global__ __launch_bounds__(256, 2) void gemm8_k(
    const ushort_t* __restrict__ A, const ushort_t* __restrict__ Bt,
    const float* __restrict__ b1, const float* __restrict__ b2,
    const float* __restrict__ b3, const float2* __restrict__ tab,
    void* __restrict__ C1, void* __restrict__ C2, void* __restrict__ C3,
    int N, int K) {
  __shared__ ushort_t LDS[32768];  // 64 KB
  ushort_t* As0 = LDS;             // [128][64] per slot
  ushort_t* As1 = LDS + 8192;
  ushort_t* Bs0 = LDS + 16384;     // [128][64] per slot
  ushort_t* Bs1 = LDS + 24576;

  const int nwg = gridDim.x * gridDim.y;
  const int orig = blockIdx.y * gridDim.x + blockIdx.x;
  const int qq = nwg >> 3;
  const int swz = (orig & 7) * qq + (orig >> 3);
  const int bx = swz % gridDim.x, by = swz / gridDim.x;

  const int tid = threadIdx.x;
  const int lane = tid & 63;
  const int lr = lane & 15, lg = lane >> 4;
  const int w = tid >> 6, wm = w >> 1, wn = w & 1;
  const int row0 = by * 128, col0 = bx * 128;

  f32x4 acc[4][4];
#pragma unroll
  for (int i = 0; i < 4; ++i)
#pragma unroll
    for (int j = 0; j < 4; ++j) acc[i][j] = (f32x4){0.f, 0.f, 0.f, 0.f};

#define STAGE(ASL, BSL, KT)                                                  \
  {                                                                          \
    _Pragma("unroll") for (int i = 0; i < 4; ++i) {                          \
      int u = tid + i * 256;                                                 \
      int r = u >> 3, ch = u & 7;                                            \
      int gch = ch ^ (r & 7);                                                \
      __builtin_amdgcn_global_load_lds(                                      \
          (const __attribute__((address_space(1))) void*)(                   \
              A + (size_t)(row0 + r) * K + (KT) * 64 + gch * 8),             \
          (__attribute__((address_space(3))) void*)((ASL) + u * 8), 16, 0, 0); \
    }                                                                        \
    _Pragma("unroll") for (int i = 0; i < 4; ++i) {                          \
      int u = tid + i * 256;                                                 \
      int r = u >> 3, ch = u & 7;                                            \
      int gch = ch ^ (r & 7);                                                \
      __builtin_amdgcn_global_load_lds(                                      \
          (const __attribute__((address_space(1))) void*)(                   \
              Bt + (size_t)(col0 + r) * K + (KT) * 64 + gch * 8),            \
          (__attribute__((address_space(3))) void*)((BSL) + u * 8), 16, 0, 0); \
    }                                                                        \
  }

  const int nkt = K >> 6;  // K-tiles of 64
  // prologue: fill both slots
  STAGE(As0, Bs0, 0);
  STAGE(As1, Bs1, 1);

  for (int kt = 0; kt < nkt; ++kt) {
    const int sl = kt & 1;
    const ushort_t* as = sl ? As1 : As0;
    const ushort_t* bs = sl ? Bs1 : Bs0;
    ushort_t* asw = sl ? As1 : As0;
    ushort_t* bsw = sl ? Bs1 : Bs0;

    if (kt + 2 < nkt) { VMCNT(8); } else { VMCNT(0); }
    SBAR();  // slot sl visible to all waves

    __builtin_amdgcn_s_setprio(1);
#pragma unroll
    for (int ki = 0; ki < 2; ++ki) {
      bf16x8 af[4], bfr[4];
#pragma unroll
      for (int mi = 0; mi < 4; ++mi) {
        int r = wm * 64 + mi * 16 + lr;
        int sch = (ki * 4 + lg) ^ (r & 7);
        af[mi] = *(const bf16x8*)&as[r * 64 + sch * 8];
      }
#pragma unroll
      for (int ni = 0; ni < 4; ++ni) {
        int r = wn * 64 + ni * 16 + lr;
        int sch = (ki * 4 + lg) ^ (r & 7);
        bfr[ni] = *(const bf16x8*)&bs[r * 64 + sch * 8];
      }
#pragma unroll
      for (int mi = 0; mi < 4; ++mi)
#pragma unroll
        for (int ni = 0; ni < 4; ++ni)
          acc[mi][ni] = __builtin_amdgcn_mfma_f32_16x16x32_bf16(
              af[mi], bfr[ni], acc[mi][ni], 0, 0, 0);
    }
    __builtin_amdgcn_s_setprio(0);
    SBAR();  // all waves done reading slot sl
    if (kt + 2 < nkt) STAGE(asw, bsw, kt + 2);
  }
#undef STAGE

  // ---- epilogue: per-wave private LDS restage (no cross-wave barrier)
  float* Ep = (float*)LDS + w * (16 * 68);  // 16 rows x 68 (pad) f32 per wave
  const int er = lane >> 2;                 // 0..15
  const int ec = (lane & 3) * 16;           // 0..48
  const int gcol = col0 + wn * 64 + ec;

#pragma unroll
  for (int mi = 0; mi < 4; ++mi) {
#pragma unroll
    for (int ni = 0; ni < 4; ++ni)
#pragma unroll
      for (int j = 0; j < 4; ++j)
        Ep[(lg * 4 + j) * 68 + ni * 16 + lr] = acc[mi][ni][j];
    LGKM0();

    const int grow = row0 + wm * 64 + mi * 16 + er;
    float v[16];
#pragma unroll
    for (int q4 = 0; q4 < 4; ++q4)
      *(float4*)(v + q4 * 4) = *(const float4*)&Ep[er * 68 + ec + q4 * 4];
    LGKM0();  // reads complete before next mi's writes

    if (EPI == 0) {
      float* Cp = (float*)C1 + (size_t)grow * N + gcol;
#pragma unroll
      for (int q4 = 0; q4 < 4; ++q4) {
        float4 bb = *(const float4*)&b1[gcol + q4 * 4];
        float4 o;
        o.x = v[q4 * 4 + 0] + bb.x; o.y = v[q4 * 4 + 1] + bb.y;
        o.z = v[q4 * 4 + 2] + bb.z; o.w = v[q4 * 4 + 3] + bb.w;
        *(float4*)(Cp + q4 * 4) = o;
      }
    } else {
      const int s = grow & (S_ - 1);
      ushort_t hs[16];
      ushort_t* Cp;
      if (gcol < DM_) {               // Q: RoPE
        const float2* tp = tab + (size_t)s * 64 + ((gcol & 127) >> 1);
        const float* bb = b1 + gcol;
#pragma unroll
        for (int p = 0; p < 8; ++p) {
          float2 cs = tp[p];
          float v0 = v[2 * p] + bb[2 * p], v1 = v[2 * p + 1] + bb[2 * p + 1];
          hs[2 * p]     = f2bf(v0 * cs.x - v1 * cs.y);
          hs[2 * p + 1] = f2bf(v0 * cs.y + v1 * cs.x);
        }
        Cp = (ushort_t*)C1 + (size_t)grow * DM_ + gcol;
      } else if (gcol < DM_ + DK_) {  // K: RoPE
        const int c = gcol - DM_;
        const float2* tp = tab + (size_t)s * 64 + (c >> 1);
        const float* bb = b2 + c;
#pragma unroll
        for (int p = 0; p < 8; ++p) {
          float2 cs = tp[p];
          float v0 = v[2 * p] + bb[2 * p], v1 = v[2 * p + 1] + bb[2 * p + 1];
          hs[2 * p]     = f2bf(v0 * cs.x - v1 * cs.y);
          hs[2 * p + 1] = f2bf(v0 * cs.y + v1 * cs.x);
        }
        Cp = (ushort_t*)C2 + (size_t)grow * DK_ + c;
      } else {                        // V: plain bias
        const int c = gcol - DM_ - DK_;
#pragma unroll
        for (int kk = 0; kk < 16; ++kk) hs[kk] = f2bf(v[kk] + b3[c + kk]);
        Cp = (ushort_t*)C3 + (size_t)grow * DK_ + c;
      }
      uint4 u0, u1;
      u0.x = (uint_t)hs[0] | ((uint_t)hs[1] << 16);
      u0.y = (uint_t)hs[2] | ((uint_t)hs[3] << 16);
      u0.z = (uint_t)hs[4] | ((uint_t)hs[5] << 16);
      u0.w = (uint_t)hs[6] | ((uint_t)hs[7] << 16);
      u1.x = (uint_t)hs[8] | ((uint_t)hs[9] << 16);
      u1.y = (uint_t)hs[10] | ((uint_t)hs[11] << 16);
      u1.z = (uint_t)hs[12] | ((uint_t)hs[13] << 16);
      u1.w = (uint_t)hs[14] | ((uint_t)hs[15] << 16);
      ((uint4*)Cp)[0] = u0;
      ((uint4*)Cp)[1] = u1;
    }
  }
}

// ---------------------------------------------------------------------------
// Causal MQA flash attention v7: 32x32x16 MFMA, in-register P, balanced
// A/B waves, 128-kv macro-staging, exp2-domain softmax + T13 defer-max.
// ---------------------------------------------------------------------------
__global__ __launch_bounds__(512) void attn_mfma7_k(
    const ushort_t* __restrict__ Q, const ushort_t* __restrict__ K,
    const ushort_t* __restrict__ Vt, ushort_t* __restrict__ O) {
  __shared__ ushort_t Ksh[128][136];   // [kv][d]
  __shared__ ushort_t Vsh[128][136];   // [d][kv] (V^T), kv = 128 per macro

  const int bx = blockIdx.x;          // 0..31
  const int hg = blockIdx.y, b = blockIdx.z;
  const int tid = threadIdx.x;
  const int w = tid >> 6, lane = tid & 63;
  const int lq = lane & 31, hi = lane >> 5;
  const int h = hg * 4 + (w & 3);
  const int qt = (w < 4) ? bx : (63 - bx);
  const int q0 = qt * 32;
  const int qg = q0 + lq;
  const int nt = (qt >> 1) + 1;                 // 64-kv steps this wave
  const int ntB = ((63 - bx) >> 1) + 1;         // max 64-kv steps in block
  const int nT = (ntB + 1) >> 1;                // 128-kv macro steps
  const size_t bS = (size_t)b * S_;

  bf16x8 qf[8];
  {
    const ushort_t* qp = Q + (bS + qg) * DM_ + h * DK_ + hi * 8;
#pragma unroll
    for (int kg = 0; kg < 8; ++kg) qf[kg] = *(const bf16x8*)(qp + kg * 16);
  }

  f32x16 oacc[4];
#pragma unroll
  for (int dt = 0; dt < 4; ++dt)
#pragma unroll
    for (int i = 0; i < 16; ++i) oacc[dt][i] = 0.f;
  float m = -INFINITY, l = 0.f;

  bf16x8 kreg[4], vreg[4];
#define ISSUE_LOADS(T0)                                                      \
  {                                                                          \
    const int kv_ = (T0) * 128;                                              \
    _Pragma("unroll") for (int i = 0; i < 4; ++i) {                          \
      int u = tid + i * 512;                                                 \
      kreg[i] = *(const bf16x8*)(K + (bS + kv_ + (u >> 4)) * DK_ + (u & 15) * 8); \
      vreg[i] = *(const bf16x8*)(Vt + ((size_t)b * DK_ + (u >> 4)) * S_ + kv_ + (u & 15) * 8); \
    }                                                                        \
  }

  ISSUE_LOADS(0);

  for (int T = 0; T < nT; ++T) {
    __syncthreads();  // previous macro-tile's LDS reads done
#pragma unroll
    for (int i = 0; i < 4; ++i) {
      int u = tid + i * 512;
      *(bf16x8*)&Ksh[u >> 4][(u & 15) * 8] = kreg[i];
      *(bf16x8*)&Vsh[u >> 4][(u & 15) * 8] = vreg[i];
    }
    if (T + 1 < nT) ISSUE_LOADS(T + 1);
    __syncthreads();  // macro-tile staged

#pragma unroll
    for (int hf = 0; hf < 2; ++hf) {
      const int s64 = 2 * T + hf;
      if (s64 < nt) {
        const int kv0 = s64 * 64;
        const int ko = hf * 64;

        f32x16 st[2];
#pragma unroll
        for (int kt = 0; kt < 2; ++kt)
#pragma unroll
          for (int i = 0; i < 16; ++i) st[kt][i] = 0.f;
        __builtin_amdgcn_s_setprio(1);
#pragma unroll
        for (int kg = 0; kg < 8; ++kg) {
          bf16x8 kf0 = *(const bf16x8*)&Ksh[ko + lq][kg * 16 + hi * 8];
          bf16x8 kf1 = *(const bf16x8*)&Ksh[ko + 32 + lq][kg * 16 + hi * 8];
          st[0] = __builtin_amdgcn_mfma_f32_32x32x16_bf16(kf0, qf[kg], st[0], 0, 0, 0);
          st[1] = __builtin_amdgcn_mfma_f32_32x32x16_bf16(kf1, qf[kg], st[1], 0, 0, 0);
        }
        __builtin_amdgcn_s_setprio(0);

        const float SCL2 = 0.1275174348767325f;  // (1/sqrt(128)) * log2(e)
        const bool need_mask = (kv0 + 63) > q0;
        float tmax = -INFINITY;
#pragma unroll
        for (int kt = 0; kt < 2; ++kt)
#pragma unroll
          for (int r = 0; r < 16; ++r) {
            float s = st[kt][r] * SCL2;
            if (need_mask) {
              int kvi = kv0 + kt * 32 + (r & 3) + 8 * (r >> 2) + 4 * hi;
              if (kvi > qg) s = -INFINITY;
            }
            st[kt][r] = s;
            tmax = fmaxf(tmax, s);
          }
        tmax = fmaxf(tmax, __shfl_xor(tmax, 32));
        if (__any(tmax > m + 8.f)) {  // T13 defer-max
          float mnew = fmaxf(m, tmax);
          float corr = exp2_fast(m - mnew);
          l *= corr;
#pragma unroll
          for (int dt = 0; dt < 4; ++dt)
#pragma unroll
            for (int i = 0; i < 16; ++i) oacc[dt][i] *= corr;
          m = mnew;
        }
        float psum = 0.f;
#pragma unroll
        for (int kt = 0; kt < 2; ++kt)
#pragma unroll
          for (int r = 0; r < 16; ++r) {
            float p = exp2_fast(st[kt][r] - m);
            st[kt][r] = p;
            psum += p;
          }
        psum += __shfl_xor(psum, 32);
        l += psum;

        uint_t wn2[2][4][2], wp2[2][4][2];
#pragma unroll
        for (int kt = 0; kt < 2; ++kt)
#pragma unroll
          for (int rb = 0; rb < 4; ++rb)
#pragma unroll
            for (int p = 0; p < 2; ++p) {
              wn2[kt][rb][p] = cvt_pk_bf16(st[kt][4 * rb + 2 * p],
                                           st[kt][4 * rb + 2 * p + 1]);
              wp2[kt][rb][p] = (uint_t)__shfl_xor((int)wn2[kt][rb][p], 32);
            }
        bf16x8 pf[4];
#pragma unroll
        for (int ks = 0; ks < 4; ++ks) {
          const int kt = ks >> 1, rb = 2 * (ks & 1);
          uint4 u;
          u.x = hi ? wp2[kt][rb + 1][0] : wn2[kt][rb][0];
          u.y = hi ? wp2[kt][rb + 1][1] : wn2[kt][rb][1];
          u.z = hi ? wn2[kt][rb + 1][0] : wp2[kt][rb][0];
          u.w = hi ? wn2[kt][rb + 1][1] : wp2[kt][rb][1];
          pf[ks] = *(bf16x8*)&u;
        }

        __builtin_amdgcn_s_setprio(1);
#pragma unroll
        for (int dt = 0; dt < 4; ++dt)
#pragma unroll
          for (int ks = 0; ks < 4; ++ks) {
            bf16x8 vf = *(const bf16x8*)&Vsh[dt * 32 + lq][ko + ks * 16 + hi * 8];
            oacc[dt] = __builtin_amdgcn_mfma_f32_32x32x16_bf16(vf, pf[ks], oacc[dt], 0, 0, 0);
          }
        __builtin_amdgcn_s_setprio(0);
      }
    }
  }
#undef ISSUE_LOADS

  const float invl = 1.0f / l;
  ushort_t* op = O + (bS + qg) * DM_ + h * DK_;
#pragma unroll
  for (int dt = 0; dt < 4; ++dt)
#pragma unroll
    for (int rb = 0; rb < 4; ++rb) {
      uint2 pk;
      pk.x = cvt_pk_bf16(oacc[dt][4 * rb + 0] * invl,
                         oacc[dt][4 * rb + 1] * invl);
      pk.y = cvt_pk_bf16(oacc[dt][4 * rb + 2] * invl,
                         oacc[dt][4 * rb + 3] * invl);
      *(uint2*)(op + dt * 32 + 8 * rb + 4 * hi) = pk;
    }
}

// ---------------------------------------------------------------------------
extern "C" void kernel_launch(void* const* d_in, const int* in_sizes, int n_in,
                              void* d_out, int out_size, void* d_ws,
                              size_t ws_size, hipStream_t stream) {
  const float* x  = (const float*)d_in[0];
  const int*   tp = (const int*)d_in[1];
  const float* Wq = (const float*)d_in[2];
  const float* bq = (const float*)d_in[3];
  const float* Wk = (const float*)d_in[4];
  const float* bk = (const float*)d_in[5];
  const float* Wv = (const float*)d_in[6];
  const float* bv = (const float*)d_in[7];
  const float* Wo = (const float*)d_in[8];
  const float* bo = (const float*)d_in[9];
  float* out = (float*)d_out;

  const int NQKV = DM_ + 2 * DK_;  // 2304
  ushort_t* Xbf   = (ushort_t*)d_ws;                    // M*DM     16 MB
  ushort_t* WqkvT = Xbf + (size_t)M_ * DM_;             // 2304*DM  9.5 MB
  ushort_t* WoT   = WqkvT + (size_t)NQKV * DM_;         // DM*DM    8 MB
  ushort_t* Qbf   = WoT + (size_t)DM_ * DM_;            // M*DM     16 MB
  ushort_t* Kbf   = Qbf + (size_t)M_ * DM_;             // M*DK     1 MB
  ushort_t* Vbf   = Kbf + (size_t)M_ * DK_;             // M*DK     1 MB
  ushort_t* Vtb   = Vbf + (size_t)M_ * DK_;             // B*DK*S   1 MB
  float2*   tab   = (float2*)(Vtb + (size_t)M_ * DK_);  // S*64     1 MB
  ushort_t* ATb   = Xbf;  // alias: Xbf dead after QKV projection

  cvt_bf16_k<<<(M_ * DM_ / 4 + 255) / 256, 256, 0, stream>>>(x, Xbf, M_ * DM_);
  tconv_k<<<dim3(DM_ / 64, DM_ / 64), 256, 0, stream>>>(Wq, WqkvT, DM_, DM_);
  tconv_k<<<dim3(DK_ / 64, DM_ / 64), 256, 0, stream>>>(
      Wk, WqkvT + (size_t)DM_ * DM_, DM_, DK_);
  tconv_k<<<dim3(DK_ / 64, DM_ / 64), 256, 0, stream>>>(
      Wv, WqkvT + (size_t)(DM_ + DK_) * DM_, DM_, DK_);
  tconv_k<<<dim3(DM_ / 64, DM_ / 64), 256, 0, stream>>>(Wo, WoT, DM_, DM_);
  rope_tab_k<<<S_ * 64 / 256, 256, 0, stream>>>(tp, tab);

  // Fused QKV projection (counted-vmcnt GEMM; Q,K get RoPE; bf16 out)
  gemm8_k<1><<<dim3(NQKV / 128, M_ / 128), 256, 0, stream>>>(
      Xbf, WqkvT, bq, bk, bv, tab, (void*)Qbf, (void*)Kbf, (void*)Vbf,
      NQKV, DM_);

  // V -> V^T per batch
  vtrans_k<<<dim3(S_ / 64, DK_ / 64, B_), 256, 0, stream>>>(Vbf, Vtb);

  // Causal MQA attention v7
  attn_mfma7_k<<<dim3(S_ / 64, H_ / 4, B_), 512, 0, stream>>>(
      Qbf, Kbf, Vtb, ATb);

  // Output projection (counted-vmcnt GEMM, fp32 out)
  gemm8_k<0><<<dim3(DM_ / 128, M_ / 128), 256, 0, stream>>>(
      ATb, WoT, bo, nullptr, nullptr, nullptr, (void*)out, nullptr, nullptr,
      DM_, DM_);
}